// Round 6
// baseline (550.886 us; speedup 1.0000x reference)
//
#include <hip/hip_runtime.h>

// RGCN bipartite, FP32 in/out. Round 6 (= round 5 + divergent-shfl fix):
//   - 4 fused (gemm || agg) stage dispatches via block-range split.
//   - agg: preload up to 64 edge indices+scales in ONE parallel csr load;
//     distribution loop is WAVE-UNIFORM (all lanes run all iterations, shfl
//     sources clamped, out-of-range scale zeroed) -- no shfl under divergence.
//   - setup fused to 4 dispatches; GEMM = round-4 shape (no spills).

#define NA 50000
#define NB 10000
#define NE 300000

typedef unsigned short u16;
typedef unsigned int u32;
typedef __attribute__((ext_vector_type(8))) short short8;
typedef __attribute__((ext_vector_type(4))) float f32x4;

__device__ __forceinline__ float bf2f(u16 h){
  union { u32 u; float f; } x; x.u = ((u32)h) << 16; return x.f;
}
__device__ __forceinline__ u16 f2bf(float f){
  union { float f; u32 u; } x; x.f = f;
  u32 r = (x.u + 0x7FFFu + ((x.u >> 16) & 1u)) >> 16;   // RNE
  return (u16)r;
}

// ================= setup 0: zero ints + cvt x_a to bf16 + pack W ===========
__global__ __launch_bounds__(256) void setup0_kernel(
    int* __restrict__ z, int nz,
    const float* __restrict__ xa, u16* __restrict__ xa16, int nx,
    const float* __restrict__ W1b, const float* __restrict__ W1i,
    const float* __restrict__ W2b, const float* __restrict__ W2i,
    u16* __restrict__ pwh, u16* __restrict__ pwl){
  int g = blockIdx.x * blockDim.x + threadIdx.x;
  int s = gridDim.x * blockDim.x;
  for (int i = g; i < nz; i += s) z[i] = 0;
  for (int i = g * 4; i < nx; i += s * 4){
    float4 v = *(const float4*)(xa + i);
    ushort4 o; o.x = f2bf(v.x); o.y = f2bf(v.y); o.z = f2bf(v.z); o.w = f2bf(v.w);
    *(ushort4*)(xa16 + i) = o;
  }
  const int total = 65536 + 65536 + 32768 + 32768;
  for (int t = g; t < total; t += s){
    const float* W; int N; int tt;
    if (t < 65536)       { W = W1b; N = 256; tt = t; }
    else if (t < 131072) { W = W1i; N = 256; tt = t - 65536; }
    else if (t < 163840) { W = W2b; N = 128; tt = t - 131072; }
    else                 { W = W2i; N = 128; tt = t - 163840; }
    int j = tt & 7, lane = (tt >> 3) & 63, tile = tt >> 9;
    int nT = N >> 4;
    int nt = tile % nT, kt = tile / nT;
    int k = kt * 32 + ((lane >> 4) << 3) + j;
    int n = nt * 16 + (lane & 15);
    float v = W[k * N + n];
    u16 hi = f2bf(v);
    pwh[t] = hi;
    pwl[t] = f2bf(v - bf2f(hi));
  }
}

// ================= degree histograms =======================================
__global__ void hist_kernel(const int* __restrict__ bs, const int* __restrict__ bd,
                            const int* __restrict__ isc, const int* __restrict__ idt,
                            int* __restrict__ c_bs, int* __restrict__ c_bd,
                            int* __restrict__ c_is, int* __restrict__ c_id){
  int g = blockIdx.x * blockDim.x + threadIdx.x;
  int s = gridDim.x * blockDim.x;
  for (int e = g; e < NE; e += s){
    atomicAdd(&c_bs[bs[e]], 1);
    atomicAdd(&c_bd[bd[e]], 1);
    atomicAdd(&c_is[isc[e]], 1);
    atomicAdd(&c_id[idt[e]], 1);
  }
}

// ============ scan (blocks 0,1) + scales (blocks 2..) fused ================
__global__ __launch_bounds__(1024) void scan_scales_kernel(
    const int* __restrict__ c_bs, const int* __restrict__ c_bd,
    const int* __restrict__ c_is, const int* __restrict__ c_id,
    int* __restrict__ off_bel, int* __restrict__ off_inc,
    float* __restrict__ s_ob, float* __restrict__ s_ib,
    float* __restrict__ s_oi, float* __restrict__ s_ii){
  if (blockIdx.x >= 2){
    int g = (blockIdx.x - 2) * blockDim.x + threadIdx.x;
    int s = (gridDim.x - 2) * blockDim.x;
    for (int i = g; i < NA; i += s){
      int a = c_bs[i]; s_ob[i] = rsqrtf((float)(a > 1 ? a : 1));
      int b = c_id[i]; s_ii[i] = rsqrtf((float)(b > 1 ? b : 1));
      if (i < NB){
        int c = c_bd[i]; s_ib[i] = rsqrtf((float)(c > 1 ? c : 1));
        int d = c_is[i]; s_oi[i] = rsqrtf((float)(d > 1 ? d : 1));
      }
    }
    return;
  }
  const int* cnt; int* off; int n;
  if (blockIdx.x == 0){ cnt = c_bd; off = off_bel; n = NB; }
  else                { cnt = c_id; off = off_inc; n = NA; }
  __shared__ int wsum[16];
  __shared__ int carry, chunkTot;
  int tid = threadIdx.x, lane = tid & 63, wid = tid >> 6;
  if (tid == 0) carry = 0;
  __syncthreads();
  for (int base = 0; base < n; base += 4096){
    int i0 = base + tid * 4;
    int v[4];
#pragma unroll
    for (int r = 0; r < 4; ++r){ int idx = i0 + r; v[r] = (idx < n) ? cnt[idx] : 0; }
    int s = v[0] + v[1] + v[2] + v[3];
    int x = s;
#pragma unroll
    for (int d = 1; d < 64; d <<= 1){ int t = __shfl_up(x, d, 64); if (lane >= d) x += t; }
    if (lane == 63) wsum[wid] = x;
    __syncthreads();
    if (wid == 0){
      int ws = (lane < 16) ? wsum[lane] : 0;
#pragma unroll
      for (int d = 1; d < 16; d <<= 1){ int t = __shfl_up(ws, d, 64); if (lane >= d) ws += t; }
      if (lane < 16) wsum[lane] = ws;
      if (lane == 15) chunkTot = ws;
    }
    __syncthreads();
    int waveBase = (wid == 0) ? 0 : wsum[wid - 1];
    int run = carry + waveBase + (x - s);
#pragma unroll
    for (int r = 0; r < 4; ++r){ int idx = i0 + r; if (idx < n) off[idx] = run; run += v[r]; }
    __syncthreads();
    if (tid == 0) carry += chunkTot;
    __syncthreads();
  }
  if (tid == 0) off[n] = carry;
}

// ================= CSR fill ================================================
__global__ void fill_kernel(const int* __restrict__ bs, const int* __restrict__ bd,
                            const int* __restrict__ isc, const int* __restrict__ idt,
                            const int* __restrict__ off_bel, const int* __restrict__ off_inc,
                            int* __restrict__ cur_bel, int* __restrict__ cur_inc,
                            int* __restrict__ csr_bel, int* __restrict__ csr_inc){
  int g = blockIdx.x * blockDim.x + threadIdx.x;
  int s = gridDim.x * blockDim.x;
  for (int e = g; e < NE; e += s){
    int d0 = bd[e];
    int p0 = off_bel[d0] + atomicAdd(&cur_bel[d0], 1);
    csr_bel[p0] = bs[e];
    int d1 = idt[e];
    int p1 = off_inc[d1] + atomicAdd(&cur_inc[d1], 1);
    csr_inc[p1] = isc[e];
  }
}

// ================= agg device fn ===========================================
// one wave per dst row; LPE lanes cover one edge row (16B/lane), EPI edges/iter.
// Up to 64 indices+scales preloaded with ONE parallel csr read. Distribution
// loop is WAVE-UNIFORM: every lane runs every iteration; shfl source indices
// are clamped in-range and out-of-range contributions get scale 0 (so no
// __shfl ever executes under divergent exec).  Tail (deg>64): direct loads.
template<int NCOL, int OUTBF>
__device__ __forceinline__ void agg_dev(int blk, const u16* __restrict__ X,
                                        const float* __restrict__ ss,
                                        const int* __restrict__ off,
                                        const int* __restrict__ csr,
                                        float* __restrict__ Pf,
                                        u16* __restrict__ P16, int nDst,
                                        const float* __restrict__ rs,
                                        const float* __restrict__ bias,
                                        int doRelu){
  const int LPE = NCOL / 8;       // 32 (NCOL=256) or 16 (NCOL=128)
  const int EPI = 64 / LPE;       // 2 or 4
  int wave = blk * 4 + (threadIdx.x >> 6);
  int lane = threadIdx.x & 63;
  if (wave >= nDst) return;
  int b0 = off[wave], b1 = off[wave + 1];
  int deg = b1 - b0;
  int part = lane / LPE;
  int cl = lane & (LPE - 1);
  int c = cl * 8;
  float a0[8], a1[8];
#pragma unroll
  for (int t = 0; t < 8; ++t){ a0[t] = 0.f; a1[t] = 0.f; }
  // ---- preload up to 64 indices + scales (one parallel shot) ----
  int idx = 0; float sc = 0.f;
  if (lane < deg){
    idx = csr[b0 + lane];
    sc = ss ? ss[idx] : 1.f;
  }
  int lim = deg < 64 ? deg : 64;   // wave-uniform
  for (int u = 0; u < lim; u += 2 * EPI){
    int e0 = u + part, e1 = u + EPI + part;
    int t0 = e0 < lim ? e0 : 0;
    int t1 = e1 < lim ? e1 : 0;
    int s0 = __shfl(idx, t0, 64);
    float c0 = __shfl(sc, t0, 64);
    int s1 = __shfl(idx, t1, 64);
    float c1 = __shfl(sc, t1, 64);
    if (e0 >= lim) c0 = 0.f;
    if (e1 >= lim) c1 = 0.f;
    short8 v0 = *(const short8*)(X + (size_t)s0 * NCOL + c);
    short8 v1 = *(const short8*)(X + (size_t)s1 * NCOL + c);
#pragma unroll
    for (int q = 0; q < 8; ++q){
      a0[q] += bf2f((u16)v0[q]) * c0;
      a1[q] += bf2f((u16)v1[q]) * c1;
    }
  }
  // ---- tail for deg > 64 (rare): direct loads, no shfl ----
  for (int j = b0 + 64 + part; j < b1; j += EPI){
    int s0 = csr[j];
    float c0 = ss ? ss[s0] : 1.f;
    short8 v0 = *(const short8*)(X + (size_t)s0 * NCOL + c);
#pragma unroll
    for (int q = 0; q < 8; ++q) a0[q] += bf2f((u16)v0[q]) * c0;
  }
#pragma unroll
  for (int q = 0; q < 8; ++q) a0[q] += a1[q];
#pragma unroll
  for (int d = LPE; d < 64; d <<= 1){
#pragma unroll
    for (int q = 0; q < 8; ++q) a0[q] += __shfl_xor(a0[q], d, 64);
  }
  float rv = rs ? rs[wave] : 1.f;
#pragma unroll
  for (int q = 0; q < 8; ++q){
    float bv = bias ? bias[c + q] : 0.f;
    float v = a0[q] * rv + bv;
    if (doRelu) v = fmaxf(v, 0.f);
    a0[q] = v;
  }
  if (part == 0){
    if (OUTBF){
      short8 o;
#pragma unroll
      for (int q = 0; q < 8; ++q) o[q] = (short)f2bf(a0[q]);
      *(short8*)(P16 + (size_t)wave * NCOL + c) = o;
    } else {
      float4 f0; f0.x = a0[0]; f0.y = a0[1]; f0.z = a0[2]; f0.w = a0[3];
      float4 f1; f1.x = a0[4]; f1.y = a0[5]; f1.z = a0[6]; f1.w = a0[7];
      *(float4*)(Pf + (size_t)wave * NCOL + c) = f0;
      *(float4*)(Pf + (size_t)wave * NCOL + c + 4) = f1;
    }
  }
}

// ================= gemm device fn ==========================================
// C[M,N] = relu?( (A[M,256] @ W) * rs[m] + bias[n] ); fp32 via 3-term bf16
// split MFMA; single live accumulator; (1<<wpsShift) waves/strip over nt.
__device__ __forceinline__ void gemm_dev(int blk, const float* __restrict__ A,
                                         const u16* __restrict__ PWH,
                                         const u16* __restrict__ PWL,
                                         const float* __restrict__ bias,
                                         const float* __restrict__ rs,
                                         float* __restrict__ Cf,
                                         u16* __restrict__ C16,
                                         int M, int nT, int wpsShift,
                                         int doRelu){
  int wave = blk * 4 + (threadIdx.x >> 6);
  int lane = threadIdx.x & 63;
  int strips = M >> 4;
  int strip = wave >> wpsShift;
  if (strip >= strips) return;
  int slice = wave & ((1 << wpsShift) - 1);
  int ntPer = nT >> wpsShift;
  int ntStart = slice * ntPer;
  int N = nT << 4;
  int r16 = lane & 15, quad = lane >> 4;
  int m0 = strip << 4;
  const float* aBase = A + (size_t)(m0 + r16) * 256 + quad * 8;
  short8 ah[8], al[8];
#pragma unroll
  for (int kt = 0; kt < 8; ++kt){
    float4 p0 = *(const float4*)(aBase + kt * 32);
    float4 p1 = *(const float4*)(aBase + kt * 32 + 4);
    float v[8] = {p0.x, p0.y, p0.z, p0.w, p1.x, p1.y, p1.z, p1.w};
    short8 h, l;
#pragma unroll
    for (int j = 0; j < 8; ++j){
      u16 hb = f2bf(v[j]);
      h[j] = (short)hb;
      l[j] = (short)f2bf(v[j] - bf2f(hb));
    }
    ah[kt] = h; al[kt] = l;
  }
  float rscale[4];
#pragma unroll
  for (int r = 0; r < 4; ++r) rscale[r] = rs ? rs[m0 + quad * 4 + r] : 1.f;
  for (int nt = ntStart; nt < ntStart + ntPer; ++nt){
    f32x4 acc = {0.f, 0.f, 0.f, 0.f};
    const u16* bh = PWH + ((size_t)nt * 64 + lane) * 8;
    const u16* bl = PWL + ((size_t)nt * 64 + lane) * 8;
#pragma unroll
    for (int kt = 0; kt < 8; ++kt){
      short8 wh = *(const short8*)(bh + (size_t)kt * nT * 512);
      short8 wl = *(const short8*)(bl + (size_t)kt * nT * 512);
      acc = __builtin_amdgcn_mfma_f32_16x16x32_bf16(ah[kt], wh, acc, 0, 0, 0);
      acc = __builtin_amdgcn_mfma_f32_16x16x32_bf16(al[kt], wh, acc, 0, 0, 0);
      acc = __builtin_amdgcn_mfma_f32_16x16x32_bf16(ah[kt], wl, acc, 0, 0, 0);
    }
    int col = nt * 16 + r16;
    float bv = bias ? bias[col] : 0.f;
#pragma unroll
    for (int r = 0; r < 4; ++r){
      float v = acc[r] * rscale[r] + bv;
      if (doRelu) v = fmaxf(v, 0.f);
      size_t o = (size_t)(m0 + quad * 4 + r) * N + col;
      if (C16) C16[o] = f2bf(v);
      else     Cf[o] = v;
    }
  }
}

// ================= fused stage: gemm blocks then agg blocks ================
template<int NCOL, int OUTBF>
__global__ __launch_bounds__(256) void stage_kernel(
    const float* A, const u16* PWH, const u16* PWL,
    const float* gbias, const float* grs, float* GCf, u16* GC16,
    int M, int nT, int wpsShift, int gRelu, int gemmBlocks,
    const u16* X, const float* ss, const int* off, const int* csr,
    float* Pf, u16* P16, int nDst, const float* ars, const float* abias,
    int aRelu){
  int blk = blockIdx.x;
  if (blk < gemmBlocks)
    gemm_dev(blk, A, PWH, PWL, gbias, grs, GCf, GC16, M, nT, wpsShift, gRelu);
  else
    agg_dev<NCOL, OUTBF>(blk - gemmBlocks, X, ss, off, csr, Pf, P16, nDst,
                         ars, abias, aRelu);
}

extern "C" void kernel_launch(void* const* d_in, const int* in_sizes, int n_in,
                              void* d_out, int out_size, void* d_ws, size_t ws_size,
                              hipStream_t stream){
  const float* x_a = (const float*)d_in[0];
  const float* x_b = (const float*)d_in[1];
  const float* W1b = (const float*)d_in[2];
  const float* b1b = (const float*)d_in[3];
  const float* W1i = (const float*)d_in[4];
  const float* b1i = (const float*)d_in[5];
  const float* W2b = (const float*)d_in[6];
  const float* b2b = (const float*)d_in[7];
  const float* W2i = (const float*)d_in[8];
  const float* b2i = (const float*)d_in[9];
  const int* bs  = (const int*)d_in[10];
  const int* bd  = (const int*)d_in[11];
  const int* isc = (const int*)d_in[12];
  const int* idt = (const int*)d_in[13];

  char* w = (char*)d_ws;
  size_t o = 0;
  auto take = [&](size_t bytes) -> void* {
    void* p = w + o; o = (o + bytes + 255) & ~(size_t)255; return p;
  };
  // contiguous counters+cursors: one zero pass covers all 180000 ints
  int* zint = (int*)take(180000 * sizeof(int));
  int* c_bs = zint, *c_bd = zint + 50000, *c_is = zint + 60000, *c_id = zint + 70000;
  int* cur_bel = zint + 120000, *cur_inc = zint + 130000;
  int* off_bel = (int*)take((NB + 1) * sizeof(int));
  int* off_inc = (int*)take((NA + 1) * sizeof(int));
  int* csr_bel = (int*)take(NE * sizeof(int));
  int* csr_inc = (int*)take(NE * sizeof(int));
  float* s_ob = (float*)take(NA * sizeof(float));  // rsqrt deg_out bel (A)
  float* s_ib = (float*)take(NB * sizeof(float));  // rsqrt deg_in  bel (B)
  float* s_oi = (float*)take(NB * sizeof(float));  // rsqrt deg_out inc (B)
  float* s_ii = (float*)take(NA * sizeof(float));  // rsqrt deg_in  inc (A)
  u16* pwh = (u16*)take(196608 * sizeof(u16));
  u16* pwl = (u16*)take(196608 * sizeof(u16));
  u16* pwh1b = pwh, *pwh1i = pwh + 65536, *pwh2b = pwh + 131072, *pwh2i = pwh + 163840;
  u16* pwl1b = pwl, *pwl1i = pwl + 65536, *pwl2b = pwl + 131072, *pwl2i = pwl + 163840;
  u16* xa16 = (u16*)take((size_t)NA * 256 * sizeof(u16));   // x_a bf16 (gathered)
  u16* G1   = (u16*)take((size_t)NB * 256 * sizeof(u16));   // (x_b@W1i)*s_oi, bf16
  u16* H_a  = (u16*)take((size_t)NA * 256 * sizeof(u16));   // layer-1 A feats, bf16
  u16* G2   = (u16*)take((size_t)NB * 128 * sizeof(u16));   // (H_b@W2i)*s_oi, bf16
  float* P_b = (float*)take((size_t)NB * 256 * sizeof(float)); // agg out fp32 (reused)
  float* H_b = (float*)take((size_t)NB * 256 * sizeof(float)); // layer-1 B feats fp32

  float* out_a = (float*)d_out;                     // [NA,128]
  float* out_b = (float*)d_out + (size_t)NA * 128;  // [NB,128]

  // ---- setup: 4 dispatches ----
  setup0_kernel<<<1024, 256, 0, stream>>>(zint, 180000, x_a, xa16, NA * 256,
                                          W1b, W1i, W2b, W2i, pwh, pwl);
  hist_kernel<<<1172, 256, 0, stream>>>(bs, bd, isc, idt, c_bs, c_bd, c_is, c_id);
  scan_scales_kernel<<<52, 1024, 0, stream>>>(c_bs, c_bd, c_is, c_id,
                                              off_bel, off_inc,
                                              s_ob, s_ib, s_oi, s_ii);
  fill_kernel<<<1172, 256, 0, stream>>>(bs, bd, isc, idt, off_bel, off_inc,
                                        cur_bel, cur_inc, csr_bel, csr_inc);

  // ---- 4 fused stages (gemm || agg; operands ready from prior stage) ----
  // S1: G1 = (x_b@W1i)*s_oi (bf16)  ||  P_b = agg_bel(xa16 * s_ob) (fp32)
  stage_kernel<256, 0><<<625 + 2500, 256, 0, stream>>>(
      x_b, pwh1i, pwl1i, nullptr, s_oi, nullptr, G1, NB, 16, 2, 0, 625,
      xa16, s_ob, off_bel, csr_bel, P_b, nullptr, NB, nullptr, nullptr, 0);
  // S2: H_b = relu((P_b@W1b)*s_ib + b1b) (fp32) || H_a = relu(agg_inc(G1)*s_ii + b1i) (bf16)
  stage_kernel<256, 1><<<625 + 12500, 256, 0, stream>>>(
      P_b, pwh1b, pwl1b, b1b, s_ib, H_b, nullptr, NB, 16, 2, 1, 625,
      G1, nullptr, off_inc, csr_inc, nullptr, H_a, NA, s_ii, b1i, 1);
  // S3: G2 = (H_b@W2i)*s_oi (bf16)  ||  P_b = agg_bel(H_a * s_ob) (fp32)
  stage_kernel<256, 0><<<625 + 2500, 256, 0, stream>>>(
      H_b, pwh2i, pwl2i, nullptr, s_oi, nullptr, G2, NB, 8, 2, 0, 625,
      H_a, s_ob, off_bel, csr_bel, P_b, nullptr, NB, nullptr, nullptr, 0);
  // S4: out_b = (P_b@W2b)*s_ib + b2b || out_a = agg_inc(G2)*s_ii + b2i
  stage_kernel<128, 0><<<625 + 12500, 256, 0, stream>>>(
      P_b, pwh2b, pwl2b, b2b, s_ib, out_b, nullptr, NB, 8, 2, 0, 625,
      G2, nullptr, off_inc, csr_inc, out_a, nullptr, NA, s_ii, b2i, 0);
}

// Round 7
// 510.704 us; speedup vs baseline: 1.0787x; 1.0787x over previous
//
#include <hip/hip_runtime.h>

// RGCN bipartite, FP32 in/out. Round 7:
//   - UNFUSED stages (round-6 fusion shared one 88-VGPR allocation across
//     gemm+agg paths -> agg occupancy 65%->20%; separate kernels restore it).
//   - Sources PRE-SCALED (s_ob folded into xa16 cvt and S2 epilogue; s_oi in
//     inc gemms) -> agg hot loop has NO ss[src] gather: csr -> row-gather only.
//   - agg: preload 64 edge idx in one csr shot, wave-uniform chunked loop,
//     4 independent 16B gathers in flight per lane, OOB edges weight 0.
//   - GEMM: round-4 shape (single live acc, no spills), 4 waves/strip.

#define NA 50000
#define NB 10000
#define NE 300000
#define CVTB 400

typedef unsigned short u16;
typedef unsigned int u32;
typedef __attribute__((ext_vector_type(8))) short short8;
typedef __attribute__((ext_vector_type(4))) float f32x4;

__device__ __forceinline__ float bf2f(u16 h){
  union { u32 u; float f; } x; x.u = ((u32)h) << 16; return x.f;
}
__device__ __forceinline__ u16 f2bf(float f){
  union { float f; u32 u; } x; x.f = f;
  u32 r = (x.u + 0x7FFFu + ((x.u >> 16) & 1u)) >> 16;   // RNE
  return (u16)r;
}

// ============ setup0: zero counters/cursors + pack W (hi/lo bf16) ==========
__global__ __launch_bounds__(256) void setup0_kernel(
    int* __restrict__ z, int nz,
    const float* __restrict__ W1b, const float* __restrict__ W1i,
    const float* __restrict__ W2b, const float* __restrict__ W2i,
    u16* __restrict__ pwh, u16* __restrict__ pwl){
  int g = blockIdx.x * blockDim.x + threadIdx.x;
  int s = gridDim.x * blockDim.x;
  for (int i = g; i < nz; i += s) z[i] = 0;
  const int total = 65536 + 65536 + 32768 + 32768;
  for (int t = g; t < total; t += s){
    const float* W; int N; int tt;
    if (t < 65536)       { W = W1b; N = 256; tt = t; }
    else if (t < 131072) { W = W1i; N = 256; tt = t - 65536; }
    else if (t < 163840) { W = W2b; N = 128; tt = t - 131072; }
    else                 { W = W2i; N = 128; tt = t - 163840; }
    int j = tt & 7, lane = (tt >> 3) & 63, tile = tt >> 9;
    int nT = N >> 4;
    int nt = tile % nT, kt = tile / nT;
    int k = kt * 32 + ((lane >> 4) << 3) + j;
    int n = nt * 16 + (lane & 15);
    float v = W[k * N + n];
    u16 hi = f2bf(v);
    pwh[t] = hi;
    pwl[t] = f2bf(v - bf2f(hi));
  }
}

// ================= degree histograms =======================================
__global__ void hist_kernel(const int* __restrict__ bs, const int* __restrict__ bd,
                            const int* __restrict__ isc, const int* __restrict__ idt,
                            int* __restrict__ c_bs, int* __restrict__ c_bd,
                            int* __restrict__ c_is, int* __restrict__ c_id){
  int g = blockIdx.x * blockDim.x + threadIdx.x;
  int s = gridDim.x * blockDim.x;
  for (int e = g; e < NE; e += s){
    atomicAdd(&c_bs[bs[e]], 1);
    atomicAdd(&c_bd[bd[e]], 1);
    atomicAdd(&c_is[isc[e]], 1);
    atomicAdd(&c_id[idt[e]], 1);
  }
}

// ============ scan (blocks 0,1) + scales (blocks 2..) fused ================
__global__ __launch_bounds__(1024) void scan_scales_kernel(
    const int* __restrict__ c_bs, const int* __restrict__ c_bd,
    const int* __restrict__ c_is, const int* __restrict__ c_id,
    int* __restrict__ off_bel, int* __restrict__ off_inc,
    float* __restrict__ s_ob, float* __restrict__ s_ib,
    float* __restrict__ s_oi, float* __restrict__ s_ii){
  if (blockIdx.x >= 2){
    int g = (blockIdx.x - 2) * blockDim.x + threadIdx.x;
    int s = (gridDim.x - 2) * blockDim.x;
    for (int i = g; i < NA; i += s){
      int a = c_bs[i]; s_ob[i] = rsqrtf((float)(a > 1 ? a : 1));
      int b = c_id[i]; s_ii[i] = rsqrtf((float)(b > 1 ? b : 1));
      if (i < NB){
        int c = c_bd[i]; s_ib[i] = rsqrtf((float)(c > 1 ? c : 1));
        int d = c_is[i]; s_oi[i] = rsqrtf((float)(d > 1 ? d : 1));
      }
    }
    return;
  }
  const int* cnt; int* off; int n;
  if (blockIdx.x == 0){ cnt = c_bd; off = off_bel; n = NB; }
  else                { cnt = c_id; off = off_inc; n = NA; }
  __shared__ int wsum[16];
  __shared__ int carry, chunkTot;
  int tid = threadIdx.x, lane = tid & 63, wid = tid >> 6;
  if (tid == 0) carry = 0;
  __syncthreads();
  for (int base = 0; base < n; base += 4096){
    int i0 = base + tid * 4;
    int v[4];
#pragma unroll
    for (int r = 0; r < 4; ++r){ int idx = i0 + r; v[r] = (idx < n) ? cnt[idx] : 0; }
    int s = v[0] + v[1] + v[2] + v[3];
    int x = s;
#pragma unroll
    for (int d = 1; d < 64; d <<= 1){ int t = __shfl_up(x, d, 64); if (lane >= d) x += t; }
    if (lane == 63) wsum[wid] = x;
    __syncthreads();
    if (wid == 0){
      int ws = (lane < 16) ? wsum[lane] : 0;
#pragma unroll
      for (int d = 1; d < 16; d <<= 1){ int t = __shfl_up(ws, d, 64); if (lane >= d) ws += t; }
      if (lane < 16) wsum[lane] = ws;
      if (lane == 15) chunkTot = ws;
    }
    __syncthreads();
    int waveBase = (wid == 0) ? 0 : wsum[wid - 1];
    int run = carry + waveBase + (x - s);
#pragma unroll
    for (int r = 0; r < 4; ++r){ int idx = i0 + r; if (idx < n) off[idx] = run; run += v[r]; }
    __syncthreads();
    if (tid == 0) carry += chunkTot;
    __syncthreads();
  }
  if (tid == 0) off[n] = carry;
}

// ====== cvt x_a * s_ob -> bf16 (blocks < CVTB) || CSR fill (rest) ==========
__global__ __launch_bounds__(256) void cvt_fill_kernel(
    const float* __restrict__ xa, const float* __restrict__ s_ob,
    u16* __restrict__ xa16,
    const int* __restrict__ bs, const int* __restrict__ bd,
    const int* __restrict__ isc, const int* __restrict__ idt,
    const int* __restrict__ off_bel, const int* __restrict__ off_inc,
    int* __restrict__ cur_bel, int* __restrict__ cur_inc,
    int* __restrict__ csr_bel, int* __restrict__ csr_inc){
  if (blockIdx.x < CVTB){
    int g = (blockIdx.x * blockDim.x + threadIdx.x) * 4;
    int s = CVTB * blockDim.x * 4;
    for (int i = g; i < NA * 256; i += s){
      float4 v = *(const float4*)(xa + i);
      float sc = s_ob[i >> 8];
      ushort4 o;
      o.x = f2bf(v.x * sc); o.y = f2bf(v.y * sc);
      o.z = f2bf(v.z * sc); o.w = f2bf(v.w * sc);
      *(ushort4*)(xa16 + i) = o;
    }
  } else {
    int g = (blockIdx.x - CVTB) * blockDim.x + threadIdx.x;
    int s = (gridDim.x - CVTB) * blockDim.x;
    for (int e = g; e < NE; e += s){
      int d0 = bd[e];
      int p0 = off_bel[d0] + atomicAdd(&cur_bel[d0], 1);
      csr_bel[p0] = bs[e];
      int d1 = idt[e];
      int p1 = off_inc[d1] + atomicAdd(&cur_inc[d1], 1);
      csr_inc[p1] = isc[e];
    }
  }
}

// ================= aggregation =============================================
// P[dst] = epi( sum_{e->dst} X[src[e]] )   (X already src-pre-scaled)
// epi: v = sum*(rs?rs[row]:1) + (bias?bias[col]:0); relu?; v *= (ps?ps[row]:1)
// one wave per dst row; LPE lanes per edge row (16B/lane), EPI edges/step.
// 64 edge indices preloaded in ONE csr shot; wave-uniform chunked loop with
// 4 independent gathers in flight per lane; OOB edges get weight 0.
template<int NCOL, int OUTBF>
__global__ __launch_bounds__(256) void agg_kernel(
    const u16* __restrict__ X, const int* __restrict__ off,
    const int* __restrict__ csr,
    float* __restrict__ Pf, u16* __restrict__ P16, int nDst,
    const float* __restrict__ rs, const float* __restrict__ bias,
    const float* __restrict__ ps, int doRelu){
  const int LPE = NCOL / 8;       // 32 (NCOL=256) or 16 (NCOL=128)
  const int EPI = 64 / LPE;       // 2 or 4
  const int CH  = EPI * 4;        // edges per chunk (4 gathers/lane in flight)
  int wave = blockIdx.x * 4 + (threadIdx.x >> 6);
  int lane = threadIdx.x & 63;
  if (wave >= nDst) return;
  int b0 = off[wave], b1 = off[wave + 1];
  int deg = b1 - b0;
  int part = lane / LPE;
  int cl = lane & (LPE - 1);
  int c = cl * 8;
  float acc[8];
#pragma unroll
  for (int q = 0; q < 8; ++q) acc[q] = 0.f;
  int idx = 0;
  if (lane < deg) idx = csr[b0 + lane];
  int lim = deg < 64 ? deg : 64;            // wave-uniform
  for (int u = 0; u < lim; u += CH){
    const u16* addr[4]; float w[4];
#pragma unroll
    for (int k = 0; k < 4; ++k){
      int e = u + k * EPI + part;
      int t = e < lim ? e : 0;
      int s0 = __shfl(idx, t, 64);
      w[k] = e < lim ? 1.f : 0.f;
      addr[k] = X + (size_t)s0 * NCOL + c;
    }
    short8 v[4];
#pragma unroll
    for (int k = 0; k < 4; ++k) v[k] = *(const short8*)addr[k];
#pragma unroll
    for (int k = 0; k < 4; ++k)
#pragma unroll
      for (int q = 0; q < 8; ++q) acc[q] += bf2f((u16)v[k][q]) * w[k];
  }
  // tail deg > 64 (rare): direct loads, no shfl
  for (int j = b0 + 64 + part; j < b1; j += EPI){
    int s0 = csr[j];
    short8 v0 = *(const short8*)(X + (size_t)s0 * NCOL + c);
#pragma unroll
    for (int q = 0; q < 8; ++q) acc[q] += bf2f((u16)v0[q]);
  }
#pragma unroll
  for (int d = LPE; d < 64; d <<= 1){
#pragma unroll
    for (int q = 0; q < 8; ++q) acc[q] += __shfl_xor(acc[q], d, 64);
  }
  float rv = rs ? rs[wave] : 1.f;
  float pv = ps ? ps[wave] : 1.f;
#pragma unroll
  for (int q = 0; q < 8; ++q){
    float bv = bias ? bias[c + q] : 0.f;
    float v = acc[q] * rv + bv;
    if (doRelu) v = fmaxf(v, 0.f);
    acc[q] = v * pv;
  }
  if (part == 0){
    if (OUTBF){
      short8 o;
#pragma unroll
      for (int q = 0; q < 8; ++q) o[q] = (short)f2bf(acc[q]);
      *(short8*)(P16 + (size_t)wave * NCOL + c) = o;
    } else {
      float4 f0; f0.x = acc[0]; f0.y = acc[1]; f0.z = acc[2]; f0.w = acc[3];
      float4 f1; f1.x = acc[4]; f1.y = acc[5]; f1.z = acc[6]; f1.w = acc[7];
      *(float4*)(Pf + (size_t)wave * NCOL + c) = f0;
      *(float4*)(Pf + (size_t)wave * NCOL + c + 4) = f1;
    }
  }
}

// ================= GEMM ====================================================
// C[M,N] = relu?( (A[M,256] @ W) * rs[m] + bias[n] ); fp32 via 3-term bf16
// split MFMA; single live accumulator; (1<<wpsShift) waves/strip over nt.
__global__ __launch_bounds__(256) void gemm_kernel(
    const float* __restrict__ A,
    const u16* __restrict__ PWH, const u16* __restrict__ PWL,
    const float* __restrict__ bias, const float* __restrict__ rs,
    float* __restrict__ Cf, u16* __restrict__ C16,
    int M, int nT, int wpsShift, int doRelu){
  int wave = blockIdx.x * 4 + (threadIdx.x >> 6);
  int lane = threadIdx.x & 63;
  int strips = M >> 4;
  int strip = wave >> wpsShift;
  if (strip >= strips) return;
  int slice = wave & ((1 << wpsShift) - 1);
  int ntPer = nT >> wpsShift;
  int ntStart = slice * ntPer;
  int N = nT << 4;
  int r16 = lane & 15, quad = lane >> 4;
  int m0 = strip << 4;
  const float* aBase = A + (size_t)(m0 + r16) * 256 + quad * 8;
  short8 ah[8], al[8];
#pragma unroll
  for (int kt = 0; kt < 8; ++kt){
    float4 p0 = *(const float4*)(aBase + kt * 32);
    float4 p1 = *(const float4*)(aBase + kt * 32 + 4);
    float v[8] = {p0.x, p0.y, p0.z, p0.w, p1.x, p1.y, p1.z, p1.w};
    short8 h, l;
#pragma unroll
    for (int j = 0; j < 8; ++j){
      u16 hb = f2bf(v[j]);
      h[j] = (short)hb;
      l[j] = (short)f2bf(v[j] - bf2f(hb));
    }
    ah[kt] = h; al[kt] = l;
  }
  float rscale[4];
#pragma unroll
  for (int r = 0; r < 4; ++r) rscale[r] = rs ? rs[m0 + quad * 4 + r] : 1.f;
  for (int nt = ntStart; nt < ntStart + ntPer; ++nt){
    f32x4 acc = {0.f, 0.f, 0.f, 0.f};
    const u16* bh = PWH + ((size_t)nt * 64 + lane) * 8;
    const u16* bl = PWL + ((size_t)nt * 64 + lane) * 8;
#pragma unroll
    for (int kt = 0; kt < 8; ++kt){
      short8 wh = *(const short8*)(bh + (size_t)kt * nT * 512);
      short8 wl = *(const short8*)(bl + (size_t)kt * nT * 512);
      acc = __builtin_amdgcn_mfma_f32_16x16x32_bf16(ah[kt], wh, acc, 0, 0, 0);
      acc = __builtin_amdgcn_mfma_f32_16x16x32_bf16(al[kt], wh, acc, 0, 0, 0);
      acc = __builtin_amdgcn_mfma_f32_16x16x32_bf16(ah[kt], wl, acc, 0, 0, 0);
    }
    int col = nt * 16 + r16;
    float bv = bias ? bias[col] : 0.f;
#pragma unroll
    for (int r = 0; r < 4; ++r){
      float v = acc[r] * rscale[r] + bv;
      if (doRelu) v = fmaxf(v, 0.f);
      size_t o = (size_t)(m0 + quad * 4 + r) * N + col;
      if (C16) C16[o] = f2bf(v);
      else     Cf[o] = v;
    }
  }
}

extern "C" void kernel_launch(void* const* d_in, const int* in_sizes, int n_in,
                              void* d_out, int out_size, void* d_ws, size_t ws_size,
                              hipStream_t stream){
  const float* x_a = (const float*)d_in[0];
  const float* x_b = (const float*)d_in[1];
  const float* W1b = (const float*)d_in[2];
  const float* b1b = (const float*)d_in[3];
  const float* W1i = (const float*)d_in[4];
  const float* b1i = (const float*)d_in[5];
  const float* W2b = (const float*)d_in[6];
  const float* b2b = (const float*)d_in[7];
  const float* W2i = (const float*)d_in[8];
  const float* b2i = (const float*)d_in[9];
  const int* bs  = (const int*)d_in[10];
  const int* bd  = (const int*)d_in[11];
  const int* isc = (const int*)d_in[12];
  const int* idt = (const int*)d_in[13];

  char* w = (char*)d_ws;
  size_t o = 0;
  auto take = [&](size_t bytes) -> void* {
    void* p = w + o; o = (o + bytes + 255) & ~(size_t)255; return p;
  };
  int* zint = (int*)take(180000 * sizeof(int));   // counters[120k] + cursors[60k]
  int* c_bs = zint, *c_bd = zint + 50000, *c_is = zint + 60000, *c_id = zint + 70000;
  int* cur_bel = zint + 120000, *cur_inc = zint + 130000;
  int* off_bel = (int*)take((NB + 1) * sizeof(int));
  int* off_inc = (int*)take((NA + 1) * sizeof(int));
  int* csr_bel = (int*)take(NE * sizeof(int));
  int* csr_inc = (int*)take(NE * sizeof(int));
  float* s_ob = (float*)take(NA * sizeof(float));  // rsqrt deg_out bel (A)
  float* s_ib = (float*)take(NB * sizeof(float));  // rsqrt deg_in  bel (B)
  float* s_oi = (float*)take(NB * sizeof(float));  // rsqrt deg_out inc (B)
  float* s_ii = (float*)take(NA * sizeof(float));  // rsqrt deg_in  inc (A)
  u16* pwh = (u16*)take(196608 * sizeof(u16));
  u16* pwl = (u16*)take(196608 * sizeof(u16));
  u16* pwh1b = pwh, *pwh1i = pwh + 65536, *pwh2b = pwh + 131072, *pwh2i = pwh + 163840;
  u16* pwl1b = pwl, *pwl1i = pwl + 65536, *pwl2b = pwl + 131072, *pwl2i = pwl + 163840;
  u16* xa16 = (u16*)take((size_t)NA * 256 * sizeof(u16));   // x_a * s_ob, bf16
  u16* G1   = (u16*)take((size_t)NB * 256 * sizeof(u16));   // (x_b@W1i)*s_oi, bf16
  u16* H_a  = (u16*)take((size_t)NA * 256 * sizeof(u16));   // relu(L1 inc)*s_ob, bf16
  u16* G2   = (u16*)take((size_t)NB * 128 * sizeof(u16));   // (H_b@W2i)*s_oi, bf16
  float* P_b = (float*)take((size_t)NB * 256 * sizeof(float)); // agg out fp32 (reused)
  float* H_b = (float*)take((size_t)NB * 256 * sizeof(float)); // L1 B feats fp32

  float* out_a = (float*)d_out;                     // [NA,128]
  float* out_b = (float*)d_out + (size_t)NA * 128;  // [NB,128]

  // ---- setup ----
  setup0_kernel<<<512, 256, 0, stream>>>(zint, 180000, W1b, W1i, W2b, W2i, pwh, pwl);
  hist_kernel<<<1172, 256, 0, stream>>>(bs, bd, isc, idt, c_bs, c_bd, c_is, c_id);
  scan_scales_kernel<<<52, 1024, 0, stream>>>(c_bs, c_bd, c_is, c_id,
                                              off_bel, off_inc,
                                              s_ob, s_ib, s_oi, s_ii);
  cvt_fill_kernel<<<CVTB + 1172, 256, 0, stream>>>(x_a, s_ob, xa16,
                                                   bs, bd, isc, idt,
                                                   off_bel, off_inc,
                                                   cur_bel, cur_inc,
                                                   csr_bel, csr_inc);

  // ---- layer 1 ----
  gemm_kernel<<<625, 256, 0, stream>>>(x_b, pwh1i, pwl1i, nullptr, s_oi,
                                       nullptr, G1, NB, 16, 2, 0);
  agg_kernel<256, 0><<<2500, 256, 0, stream>>>(xa16, off_bel, csr_bel,
                                               P_b, nullptr, NB,
                                               nullptr, nullptr, nullptr, 0);
  gemm_kernel<<<625, 256, 0, stream>>>(P_b, pwh1b, pwl1b, b1b, s_ib,
                                       H_b, nullptr, NB, 16, 2, 1);
  agg_kernel<256, 1><<<12500, 256, 0, stream>>>(G1, off_inc, csr_inc,
                                                nullptr, H_a, NA,
                                                s_ii, b1i, s_ob, 1);
  // ---- layer 2 ----
  gemm_kernel<<<625, 256, 0, stream>>>(H_b, pwh2i, pwl2i, nullptr, s_oi,
                                       nullptr, G2, NB, 8, 2, 0);
  agg_kernel<256, 0><<<2500, 256, 0, stream>>>(H_a, off_bel, csr_bel,
                                               P_b, nullptr, NB,
                                               nullptr, nullptr, nullptr, 0);
  gemm_kernel<<<625, 256, 0, stream>>>(P_b, pwh2b, pwl2b, b2b, s_ib,
                                       out_b, nullptr, NB, 8, 2, 0);
  agg_kernel<128, 0><<<12500, 256, 0, stream>>>(G2, off_inc, csr_inc,
                                                out_a, nullptr, NA,
                                                s_ii, b2i, nullptr, 0);
}

// Round 8
// 432.007 us; speedup vs baseline: 1.2752x; 1.1822x over previous
//
#include <hip/hip_runtime.h>

// RGCN bipartite, FP32 in/out. Round 8:
//   - MERGED inc aggregation: G1 (256 cols) and G2 (128 cols) interleaved in
//     one 384-u16-stride buffer; ONE csr_inc pass produces H_a AND out_a
//     (round-7 ran two 60us latency-bound passes over the same graph).
//   - Non-temporal stores for all large outputs (stop write-streams evicting
//     L2-resident gather sources).
//   - bel agg: round-7 shape, epilogue-free (only fp32 P_b out), nt stores.
//   - GEMM: round-4 shape + output (ldC, colOff) for slice writes.

#define NA 50000
#define NB 10000
#define NE 300000
#define CVTB 400

typedef unsigned short u16;
typedef unsigned int u32;
typedef __attribute__((ext_vector_type(8))) short short8;
typedef __attribute__((ext_vector_type(4))) float f32x4;
typedef __attribute__((ext_vector_type(2))) float f32x2;
typedef __attribute__((ext_vector_type(4))) unsigned short u16x4;
typedef __attribute__((ext_vector_type(2))) unsigned short u16x2;

__device__ __forceinline__ float bf2f(u16 h){
  union { u32 u; float f; } x; x.u = ((u32)h) << 16; return x.f;
}
__device__ __forceinline__ u16 f2bf(float f){
  union { float f; u32 u; } x; x.f = f;
  u32 r = (x.u + 0x7FFFu + ((x.u >> 16) & 1u)) >> 16;   // RNE
  return (u16)r;
}

// ============ setup0: zero counters/cursors + pack W (hi/lo bf16) ==========
__global__ __launch_bounds__(256) void setup0_kernel(
    int* __restrict__ z, int nz,
    const float* __restrict__ W1b, const float* __restrict__ W1i,
    const float* __restrict__ W2b, const float* __restrict__ W2i,
    u16* __restrict__ pwh, u16* __restrict__ pwl){
  int g = blockIdx.x * blockDim.x + threadIdx.x;
  int s = gridDim.x * blockDim.x;
  for (int i = g; i < nz; i += s) z[i] = 0;
  const int total = 65536 + 65536 + 32768 + 32768;
  for (int t = g; t < total; t += s){
    const float* W; int N; int tt;
    if (t < 65536)       { W = W1b; N = 256; tt = t; }
    else if (t < 131072) { W = W1i; N = 256; tt = t - 65536; }
    else if (t < 163840) { W = W2b; N = 128; tt = t - 131072; }
    else                 { W = W2i; N = 128; tt = t - 163840; }
    int j = tt & 7, lane = (tt >> 3) & 63, tile = tt >> 9;
    int nT = N >> 4;
    int nt = tile % nT, kt = tile / nT;
    int k = kt * 32 + ((lane >> 4) << 3) + j;
    int n = nt * 16 + (lane & 15);
    float v = W[k * N + n];
    u16 hi = f2bf(v);
    pwh[t] = hi;
    pwl[t] = f2bf(v - bf2f(hi));
  }
}

// ================= degree histograms =======================================
__global__ void hist_kernel(const int* __restrict__ bs, const int* __restrict__ bd,
                            const int* __restrict__ isc, const int* __restrict__ idt,
                            int* __restrict__ c_bs, int* __restrict__ c_bd,
                            int* __restrict__ c_is, int* __restrict__ c_id){
  int g = blockIdx.x * blockDim.x + threadIdx.x;
  int s = gridDim.x * blockDim.x;
  for (int e = g; e < NE; e += s){
    atomicAdd(&c_bs[bs[e]], 1);
    atomicAdd(&c_bd[bd[e]], 1);
    atomicAdd(&c_is[isc[e]], 1);
    atomicAdd(&c_id[idt[e]], 1);
  }
}

// ============ scan (blocks 0,1) + scales (blocks 2..) fused ================
__global__ __launch_bounds__(1024) void scan_scales_kernel(
    const int* __restrict__ c_bs, const int* __restrict__ c_bd,
    const int* __restrict__ c_is, const int* __restrict__ c_id,
    int* __restrict__ off_bel, int* __restrict__ off_inc,
    float* __restrict__ s_ob, float* __restrict__ s_ib,
    float* __restrict__ s_oi, float* __restrict__ s_ii){
  if (blockIdx.x >= 2){
    int g = (blockIdx.x - 2) * blockDim.x + threadIdx.x;
    int s = (gridDim.x - 2) * blockDim.x;
    for (int i = g; i < NA; i += s){
      int a = c_bs[i]; s_ob[i] = rsqrtf((float)(a > 1 ? a : 1));
      int b = c_id[i]; s_ii[i] = rsqrtf((float)(b > 1 ? b : 1));
      if (i < NB){
        int c = c_bd[i]; s_ib[i] = rsqrtf((float)(c > 1 ? c : 1));
        int d = c_is[i]; s_oi[i] = rsqrtf((float)(d > 1 ? d : 1));
      }
    }
    return;
  }
  const int* cnt; int* off; int n;
  if (blockIdx.x == 0){ cnt = c_bd; off = off_bel; n = NB; }
  else                { cnt = c_id; off = off_inc; n = NA; }
  __shared__ int wsum[16];
  __shared__ int carry, chunkTot;
  int tid = threadIdx.x, lane = tid & 63, wid = tid >> 6;
  if (tid == 0) carry = 0;
  __syncthreads();
  for (int base = 0; base < n; base += 4096){
    int i0 = base + tid * 4;
    int v[4];
#pragma unroll
    for (int r = 0; r < 4; ++r){ int idx = i0 + r; v[r] = (idx < n) ? cnt[idx] : 0; }
    int s = v[0] + v[1] + v[2] + v[3];
    int x = s;
#pragma unroll
    for (int d = 1; d < 64; d <<= 1){ int t = __shfl_up(x, d, 64); if (lane >= d) x += t; }
    if (lane == 63) wsum[wid] = x;
    __syncthreads();
    if (wid == 0){
      int ws = (lane < 16) ? wsum[lane] : 0;
#pragma unroll
      for (int d = 1; d < 16; d <<= 1){ int t = __shfl_up(ws, d, 64); if (lane >= d) ws += t; }
      if (lane < 16) wsum[lane] = ws;
      if (lane == 15) chunkTot = ws;
    }
    __syncthreads();
    int waveBase = (wid == 0) ? 0 : wsum[wid - 1];
    int run = carry + waveBase + (x - s);
#pragma unroll
    for (int r = 0; r < 4; ++r){ int idx = i0 + r; if (idx < n) off[idx] = run; run += v[r]; }
    __syncthreads();
    if (tid == 0) carry += chunkTot;
    __syncthreads();
  }
  if (tid == 0) off[n] = carry;
}

// ====== cvt x_a * s_ob -> bf16 (blocks < CVTB) || CSR fill (rest) ==========
__global__ __launch_bounds__(256) void cvt_fill_kernel(
    const float* __restrict__ xa, const float* __restrict__ s_ob,
    u16* __restrict__ xa16,
    const int* __restrict__ bs, const int* __restrict__ bd,
    const int* __restrict__ isc, const int* __restrict__ idt,
    const int* __restrict__ off_bel, const int* __restrict__ off_inc,
    int* __restrict__ cur_bel, int* __restrict__ cur_inc,
    int* __restrict__ csr_bel, int* __restrict__ csr_inc){
  if (blockIdx.x < CVTB){
    int g = (blockIdx.x * blockDim.x + threadIdx.x) * 4;
    int s = CVTB * blockDim.x * 4;
    for (int i = g; i < NA * 256; i += s){
      float4 v = *(const float4*)(xa + i);
      float sc = s_ob[i >> 8];
      u16x4 o;
      o.x = f2bf(v.x * sc); o.y = f2bf(v.y * sc);
      o.z = f2bf(v.z * sc); o.w = f2bf(v.w * sc);
      __builtin_nontemporal_store(o, (u16x4*)(xa16 + i));
    }
  } else {
    int g = (blockIdx.x - CVTB) * blockDim.x + threadIdx.x;
    int s = (gridDim.x - CVTB) * blockDim.x;
    for (int e = g; e < NE; e += s){
      int d0 = bd[e];
      int p0 = off_bel[d0] + atomicAdd(&cur_bel[d0], 1);
      csr_bel[p0] = bs[e];
      int d1 = idt[e];
      int p1 = off_inc[d1] + atomicAdd(&cur_inc[d1], 1);
      csr_inc[p1] = isc[e];
    }
  }
}

// ================= bel aggregation (dst = B, 10000 rows) ===================
// P_b[dst] = sum_{e->dst} X[src[e]]  (X pre-scaled); fp32 out, no epilogue.
// one wave per dst row; 32 lanes per edge row (16B/lane), 2 edges/step,
// 64 idx preloaded in one csr shot, wave-uniform 8-edge chunks (4 in flight).
__global__ __launch_bounds__(256) void agg_bel_kernel(
    const u16* __restrict__ X, const int* __restrict__ off,
    const int* __restrict__ csr, float* __restrict__ Pf, int nDst){
  int wave = blockIdx.x * 4 + (threadIdx.x >> 6);
  int lane = threadIdx.x & 63;
  if (wave >= nDst) return;
  int b0 = off[wave], b1 = off[wave + 1];
  int deg = b1 - b0;
  int part = lane >> 5;           // 2 parts x 32 lanes
  int cl = lane & 31;
  int c = cl * 8;
  float acc[8];
#pragma unroll
  for (int q = 0; q < 8; ++q) acc[q] = 0.f;
  int idx = 0;
  if (lane < deg) idx = csr[b0 + lane];
  int lim = deg < 64 ? deg : 64;
  for (int u = 0; u < lim; u += 8){
    const u16* addr[4]; float w[4];
#pragma unroll
    for (int k = 0; k < 4; ++k){
      int e = u + k * 2 + part;
      int t = e < lim ? e : 0;
      int s0 = __shfl(idx, t, 64);
      w[k] = e < lim ? 1.f : 0.f;
      addr[k] = X + (size_t)s0 * 256 + c;
    }
    short8 v[4];
#pragma unroll
    for (int k = 0; k < 4; ++k) v[k] = *(const short8*)addr[k];
#pragma unroll
    for (int k = 0; k < 4; ++k)
#pragma unroll
      for (int q = 0; q < 8; ++q) acc[q] += bf2f((u16)v[k][q]) * w[k];
  }
  for (int j = b0 + 64 + part; j < b1; j += 2){
    int s0 = csr[j];
    short8 v0 = *(const short8*)(X + (size_t)s0 * 256 + c);
#pragma unroll
    for (int q = 0; q < 8; ++q) acc[q] += bf2f((u16)v0[q]);
  }
#pragma unroll
  for (int q = 0; q < 8; ++q) acc[q] += __shfl_xor(acc[q], 32, 64);
  if (part == 0){
    f32x4 f0 = {acc[0], acc[1], acc[2], acc[3]};
    f32x4 f1 = {acc[4], acc[5], acc[6], acc[7]};
    __builtin_nontemporal_store(f0, (f32x4*)(Pf + (size_t)wave * 256 + c));
    __builtin_nontemporal_store(f1, (f32x4*)(Pf + (size_t)wave * 256 + c + 4));
  }
}

// ============ merged inc aggregation (dst = A, 50000 rows) =================
// One csr_inc pass over interleaved rows G12[src] = [G1 256 cols | G2 128 cols]
// (u16 stride 384). Full wave per edge: 8B/lane G1-seg + 4B/lane G2-seg.
//   H_a[row]  = relu(sum1*s_ii + b1i) * s_ob   (bf16, pre-scaled for S3a)
//   out_a[row]=      sum2*s_ii + b2i           (fp32, final output)
__global__ __launch_bounds__(256) void agg_inc2_kernel(
    const u16* __restrict__ G12, const int* __restrict__ off,
    const int* __restrict__ csr,
    const float* __restrict__ s_ii, const float* __restrict__ s_ob,
    const float* __restrict__ b1i, const float* __restrict__ b2i,
    u16* __restrict__ Ha, float* __restrict__ outa){
  int wave = blockIdx.x * 4 + (threadIdx.x >> 6);
  int lane = threadIdx.x & 63;
  if (wave >= NA) return;
  int b0 = off[wave], b1 = off[wave + 1];
  int deg = b1 - b0;
  int c1 = lane * 4;        // G1 cols c1..c1+3
  int c2 = lane * 2;        // G2 cols c2..c2+1
  float acc[6];
#pragma unroll
  for (int q = 0; q < 6; ++q) acc[q] = 0.f;
  int idx = 0;
  if (lane < deg) idx = csr[b0 + lane];
  int lim = deg < 64 ? deg : 64;
  for (int u = 0; u < lim; u += 4){
    ushort4 va[4]; ushort2 vb[4]; float w[4];
#pragma unroll
    for (int k = 0; k < 4; ++k){
      int e = u + k;
      int t = e < lim ? e : 0;
      int se = __shfl(idx, t, 64);
      w[k] = e < lim ? 1.f : 0.f;
      const u16* r = G12 + (size_t)se * 384;
      va[k] = *(const ushort4*)(r + c1);
      vb[k] = *(const ushort2*)(r + 256 + c2);
    }
#pragma unroll
    for (int k = 0; k < 4; ++k){
      acc[0] += bf2f(va[k].x) * w[k];
      acc[1] += bf2f(va[k].y) * w[k];
      acc[2] += bf2f(va[k].z) * w[k];
      acc[3] += bf2f(va[k].w) * w[k];
      acc[4] += bf2f(vb[k].x) * w[k];
      acc[5] += bf2f(vb[k].y) * w[k];
    }
  }
  for (int j = b0 + 64; j < b1; ++j){            // deg>64: ~never
    int se = csr[j];
    const u16* r = G12 + (size_t)se * 384;
    ushort4 va = *(const ushort4*)(r + c1);
    ushort2 vb = *(const ushort2*)(r + 256 + c2);
    acc[0] += bf2f(va.x); acc[1] += bf2f(va.y);
    acc[2] += bf2f(va.z); acc[3] += bf2f(va.w);
    acc[4] += bf2f(vb.x); acc[5] += bf2f(vb.y);
  }
  float sii = s_ii[wave], sob = s_ob[wave];
  float4 bb1 = *(const float4*)(b1i + c1);
  f32x2 bb2 = *(const f32x2*)(b2i + c2);
  u16x4 o1;
  o1.x = f2bf(fmaxf(acc[0] * sii + bb1.x, 0.f) * sob);
  o1.y = f2bf(fmaxf(acc[1] * sii + bb1.y, 0.f) * sob);
  o1.z = f2bf(fmaxf(acc[2] * sii + bb1.z, 0.f) * sob);
  o1.w = f2bf(fmaxf(acc[3] * sii + bb1.w, 0.f) * sob);
  __builtin_nontemporal_store(o1, (u16x4*)(Ha + (size_t)wave * 256 + c1));
  f32x2 o2 = {acc[4] * sii + bb2.x, acc[5] * sii + bb2.y};
  __builtin_nontemporal_store(o2, (f32x2*)(outa + (size_t)wave * 128 + c2));
}

// ================= GEMM ====================================================
// C[M,N] = relu?( (A[M,256] @ W) * rs[m] + bias[n] ); fp32 via 3-term bf16
// split MFMA; single live accumulator; 4 waves/strip over nt slices.
// Output: fp32 (Cf) or bf16 (C16) at row stride ldC, column offset colOff.
__global__ __launch_bounds__(256) void gemm_kernel(
    const float* __restrict__ A,
    const u16* __restrict__ PWH, const u16* __restrict__ PWL,
    const float* __restrict__ bias, const float* __restrict__ rs,
    float* __restrict__ Cf, u16* __restrict__ C16,
    int M, int nT, int wpsShift, int doRelu, int ldC, int colOff){
  int wave = blockIdx.x * 4 + (threadIdx.x >> 6);
  int lane = threadIdx.x & 63;
  int strips = M >> 4;
  int strip = wave >> wpsShift;
  if (strip >= strips) return;
  int slice = wave & ((1 << wpsShift) - 1);
  int ntPer = nT >> wpsShift;
  int ntStart = slice * ntPer;
  int r16 = lane & 15, quad = lane >> 4;
  int m0 = strip << 4;
  const float* aBase = A + (size_t)(m0 + r16) * 256 + quad * 8;
  short8 ah[8], al[8];
#pragma unroll
  for (int kt = 0; kt < 8; ++kt){
    float4 p0 = *(const float4*)(aBase + kt * 32);
    float4 p1 = *(const float4*)(aBase + kt * 32 + 4);
    float v[8] = {p0.x, p0.y, p0.z, p0.w, p1.x, p1.y, p1.z, p1.w};
    short8 h, l;
#pragma unroll
    for (int j = 0; j < 8; ++j){
      u16 hb = f2bf(v[j]);
      h[j] = (short)hb;
      l[j] = (short)f2bf(v[j] - bf2f(hb));
    }
    ah[kt] = h; al[kt] = l;
  }
  float rscale[4];
#pragma unroll
  for (int r = 0; r < 4; ++r) rscale[r] = rs ? rs[m0 + quad * 4 + r] : 1.f;
  for (int nt = ntStart; nt < ntStart + ntPer; ++nt){
    f32x4 acc = {0.f, 0.f, 0.f, 0.f};
    const u16* bh = PWH + ((size_t)nt * 64 + lane) * 8;
    const u16* bl = PWL + ((size_t)nt * 64 + lane) * 8;
#pragma unroll
    for (int kt = 0; kt < 8; ++kt){
      short8 wh = *(const short8*)(bh + (size_t)kt * nT * 512);
      short8 wl = *(const short8*)(bl + (size_t)kt * nT * 512);
      acc = __builtin_amdgcn_mfma_f32_16x16x32_bf16(ah[kt], wh, acc, 0, 0, 0);
      acc = __builtin_amdgcn_mfma_f32_16x16x32_bf16(al[kt], wh, acc, 0, 0, 0);
      acc = __builtin_amdgcn_mfma_f32_16x16x32_bf16(ah[kt], wl, acc, 0, 0, 0);
    }
    int col = nt * 16 + r16;
    float bv = bias ? bias[col] : 0.f;
#pragma unroll
    for (int r = 0; r < 4; ++r){
      float v = acc[r] * rscale[r] + bv;
      if (doRelu) v = fmaxf(v, 0.f);
      size_t o = (size_t)(m0 + quad * 4 + r) * ldC + colOff + col;
      if (C16) __builtin_nontemporal_store(f2bf(v), C16 + o);
      else     __builtin_nontemporal_store(v, Cf + o);
    }
  }
}

extern "C" void kernel_launch(void* const* d_in, const int* in_sizes, int n_in,
                              void* d_out, int out_size, void* d_ws, size_t ws_size,
                              hipStream_t stream){
  const float* x_a = (const float*)d_in[0];
  const float* x_b = (const float*)d_in[1];
  const float* W1b = (const float*)d_in[2];
  const float* b1b = (const float*)d_in[3];
  const float* W1i = (const float*)d_in[4];
  const float* b1i = (const float*)d_in[5];
  const float* W2b = (const float*)d_in[6];
  const float* b2b = (const float*)d_in[7];
  const float* W2i = (const float*)d_in[8];
  const float* b2i = (const float*)d_in[9];
  const int* bs  = (const int*)d_in[10];
  const int* bd  = (const int*)d_in[11];
  const int* isc = (const int*)d_in[12];
  const int* idt = (const int*)d_in[13];

  char* w = (char*)d_ws;
  size_t o = 0;
  auto take = [&](size_t bytes) -> void* {
    void* p = w + o; o = (o + bytes + 255) & ~(size_t)255; return p;
  };
  int* zint = (int*)take(180000 * sizeof(int));   // counters[120k] + cursors[60k]
  int* c_bs = zint, *c_bd = zint + 50000, *c_is = zint + 60000, *c_id = zint + 70000;
  int* cur_bel = zint + 120000, *cur_inc = zint + 130000;
  int* off_bel = (int*)take((NB + 1) * sizeof(int));
  int* off_inc = (int*)take((NA + 1) * sizeof(int));
  int* csr_bel = (int*)take(NE * sizeof(int));
  int* csr_inc = (int*)take(NE * sizeof(int));
  float* s_ob = (float*)take(NA * sizeof(float));  // rsqrt deg_out bel (A)
  float* s_ib = (float*)take(NB * sizeof(float));  // rsqrt deg_in  bel (B)
  float* s_oi = (float*)take(NB * sizeof(float));  // rsqrt deg_out inc (B)
  float* s_ii = (float*)take(NA * sizeof(float));  // rsqrt deg_in  inc (A)
  u16* pwh = (u16*)take(196608 * sizeof(u16));
  u16* pwl = (u16*)take(196608 * sizeof(u16));
  u16* pwh1b = pwh, *pwh1i = pwh + 65536, *pwh2b = pwh + 131072, *pwh2i = pwh + 163840;
  u16* pwl1b = pwl, *pwl1i = pwl + 65536, *pwl2b = pwl + 131072, *pwl2i = pwl + 163840;
  u16* xa16 = (u16*)take((size_t)NA * 256 * sizeof(u16));   // x_a * s_ob, bf16
  u16* G12  = (u16*)take((size_t)NB * 384 * sizeof(u16));   // [G1 256 | G2 128] bf16
  u16* H_a  = (u16*)take((size_t)NA * 256 * sizeof(u16));   // relu(L1 inc)*s_ob, bf16
  float* P_b = (float*)take((size_t)NB * 256 * sizeof(float)); // bel agg out (reused)
  float* H_b = (float*)take((size_t)NB * 256 * sizeof(float)); // L1 B feats fp32

  float* out_a = (float*)d_out;                     // [NA,128]
  float* out_b = (float*)d_out + (size_t)NA * 128;  // [NB,128]

  // ---- setup ----
  setup0_kernel<<<512, 256, 0, stream>>>(zint, 180000, W1b, W1i, W2b, W2i, pwh, pwl);
  hist_kernel<<<1172, 256, 0, stream>>>(bs, bd, isc, idt, c_bs, c_bd, c_is, c_id);
  scan_scales_kernel<<<52, 1024, 0, stream>>>(c_bs, c_bd, c_is, c_id,
                                              off_bel, off_inc,
                                              s_ob, s_ib, s_oi, s_ii);
  cvt_fill_kernel<<<CVTB + 1172, 256, 0, stream>>>(x_a, s_ob, xa16,
                                                   bs, bd, isc, idt,
                                                   off_bel, off_inc,
                                                   cur_bel, cur_inc,
                                                   csr_bel, csr_inc);

  // ---- compute ----
  // G1 = (x_b@W1i)*s_oi  -> G12[:, 0:256) (bf16, stride 384)
  gemm_kernel<<<625, 256, 0, stream>>>(x_b, pwh1i, pwl1i, nullptr, s_oi,
                                       nullptr, G12, NB, 16, 2, 0, 384, 0);
  // P_b = agg_bel(xa16)
  agg_bel_kernel<<<2500, 256, 0, stream>>>(xa16, off_bel, csr_bel, P_b, NB);
  // H_b = relu((P_b@W1b)*s_ib + b1b)
  gemm_kernel<<<625, 256, 0, stream>>>(P_b, pwh1b, pwl1b, b1b, s_ib,
                                       H_b, nullptr, NB, 16, 2, 1, 256, 0);
  // G2 = (H_b@W2i)*s_oi -> G12[:, 256:384) (bf16, stride 384)
  gemm_kernel<<<625, 256, 0, stream>>>(H_b, pwh2i, pwl2i, nullptr, s_oi,
                                       nullptr, G12, NB, 8, 2, 0, 384, 256);
  // merged inc agg: H_a (bf16, pre-scaled by s_ob) + out_a (fp32, final)
  agg_inc2_kernel<<<12500, 256, 0, stream>>>(G12, off_inc, csr_inc,
                                             s_ii, s_ob, b1i, b2i, H_a, out_a);
  // P_b = agg_bel(H_a)
  agg_bel_kernel<<<2500, 256, 0, stream>>>(H_a, off_bel, csr_bel, P_b, NB);
  // out_b = (P_b@W2b)*s_ib + b2b
  gemm_kernel<<<625, 256, 0, stream>>>(P_b, pwh2b, pwl2b, b2b, s_ib,
                                       out_b, nullptr, NB, 8, 2, 0, 128, 0);
}

// Round 9
// 409.363 us; speedup vs baseline: 1.3457x; 1.0553x over previous
//
#include <hip/hip_runtime.h>

// RGCN bipartite, FP32 in/out. Round 9:
//   - hist ALSO records each edge's rank (atomic return) -> CSR fill has NO
//     atomics (pure scatter store with precomputed slot).
//   - cvt (x_a -> bf16, unscaled) fused into the hist dispatch (block-split;
//     both paths lean-VGPR). agg_bel regains nullable ss[src] gather (proven
//     free in round 7) so cvt no longer depends on the scales.
//   - merged inc agg (one csr_inc pass -> H_a + out_a), nt stores, GEMM with
//     (ldC,colOff) slice output: all carried from round 8.

#define NA 50000
#define NB 10000
#define NE 300000
#define HB 1172     // hist blocks
#define CVTB 400    // cvt blocks

typedef unsigned short u16;
typedef unsigned int u32;
typedef __attribute__((ext_vector_type(8))) short short8;
typedef __attribute__((ext_vector_type(4))) float f32x4;
typedef __attribute__((ext_vector_type(2))) float f32x2;
typedef __attribute__((ext_vector_type(4))) unsigned short u16x4;

__device__ __forceinline__ float bf2f(u16 h){
  union { u32 u; float f; } x; x.u = ((u32)h) << 16; return x.f;
}
__device__ __forceinline__ u16 f2bf(float f){
  union { float f; u32 u; } x; x.f = f;
  u32 r = (x.u + 0x7FFFu + ((x.u >> 16) & 1u)) >> 16;   // RNE
  return (u16)r;
}

// ============ setup0: zero counters + pack W (hi/lo bf16) ==================
__global__ __launch_bounds__(256) void setup0_kernel(
    int* __restrict__ z, int nz,
    const float* __restrict__ W1b, const float* __restrict__ W1i,
    const float* __restrict__ W2b, const float* __restrict__ W2i,
    u16* __restrict__ pwh, u16* __restrict__ pwl){
  int g = blockIdx.x * blockDim.x + threadIdx.x;
  int s = gridDim.x * blockDim.x;
  for (int i = g; i < nz; i += s) z[i] = 0;
  const int total = 65536 + 65536 + 32768 + 32768;
  for (int t = g; t < total; t += s){
    const float* W; int N; int tt;
    if (t < 65536)       { W = W1b; N = 256; tt = t; }
    else if (t < 131072) { W = W1i; N = 256; tt = t - 65536; }
    else if (t < 163840) { W = W2b; N = 128; tt = t - 131072; }
    else                 { W = W2i; N = 128; tt = t - 163840; }
    int j = tt & 7, lane = (tt >> 3) & 63, tile = tt >> 9;
    int nT = N >> 4;
    int nt = tile % nT, kt = tile / nT;
    int k = kt * 32 + ((lane >> 4) << 3) + j;
    int n = nt * 16 + (lane & 15);
    float v = W[k * N + n];
    u16 hi = f2bf(v);
    pwh[t] = hi;
    pwl[t] = f2bf(v - bf2f(hi));
  }
}

// ====== hist (+edge ranks) on blocks [0,HB) || cvt x_a->bf16 on rest =======
__global__ __launch_bounds__(256) void histcvt_kernel(
    const int* __restrict__ bs, const int* __restrict__ bd,
    const int* __restrict__ isc, const int* __restrict__ idt,
    int* __restrict__ c_bs, int* __restrict__ c_bd,
    int* __restrict__ c_is, int* __restrict__ c_id,
    int* __restrict__ rank_bel, int* __restrict__ rank_inc,
    const float* __restrict__ xa, u16* __restrict__ xa16){
  if (blockIdx.x < HB){
    int g = blockIdx.x * blockDim.x + threadIdx.x;
    int s = HB * blockDim.x;
    for (int e = g; e < NE; e += s){
      atomicAdd(&c_bs[bs[e]], 1);
      rank_bel[e] = atomicAdd(&c_bd[bd[e]], 1);
      atomicAdd(&c_is[isc[e]], 1);
      rank_inc[e] = atomicAdd(&c_id[idt[e]], 1);
    }
  } else {
    int g = ((blockIdx.x - HB) * blockDim.x + threadIdx.x) * 4;
    int s = CVTB * blockDim.x * 4;
    for (int i = g; i < NA * 256; i += s){
      float4 v = *(const float4*)(xa + i);
      u16x4 o;
      o.x = f2bf(v.x); o.y = f2bf(v.y); o.z = f2bf(v.z); o.w = f2bf(v.w);
      __builtin_nontemporal_store(o, (u16x4*)(xa16 + i));
    }
  }
}

// ============ scan (blocks 0,1) + scales (blocks 2..) fused ================
__global__ __launch_bounds__(1024) void scan_scales_kernel(
    const int* __restrict__ c_bs, const int* __restrict__ c_bd,
    const int* __restrict__ c_is, const int* __restrict__ c_id,
    int* __restrict__ off_bel, int* __restrict__ off_inc,
    float* __restrict__ s_ob, float* __restrict__ s_ib,
    float* __restrict__ s_oi, float* __restrict__ s_ii){
  if (blockIdx.x >= 2){
    int g = (blockIdx.x - 2) * blockDim.x + threadIdx.x;
    int s = (gridDim.x - 2) * blockDim.x;
    for (int i = g; i < NA; i += s){
      int a = c_bs[i]; s_ob[i] = rsqrtf((float)(a > 1 ? a : 1));
      int b = c_id[i]; s_ii[i] = rsqrtf((float)(b > 1 ? b : 1));
      if (i < NB){
        int c = c_bd[i]; s_ib[i] = rsqrtf((float)(c > 1 ? c : 1));
        int d = c_is[i]; s_oi[i] = rsqrtf((float)(d > 1 ? d : 1));
      }
    }
    return;
  }
  const int* cnt; int* off; int n;
  if (blockIdx.x == 0){ cnt = c_bd; off = off_bel; n = NB; }
  else                { cnt = c_id; off = off_inc; n = NA; }
  __shared__ int wsum[16];
  __shared__ int carry, chunkTot;
  int tid = threadIdx.x, lane = tid & 63, wid = tid >> 6;
  if (tid == 0) carry = 0;
  __syncthreads();
  for (int base = 0; base < n; base += 4096){
    int i0 = base + tid * 4;
    int v[4];
#pragma unroll
    for (int r = 0; r < 4; ++r){ int idx = i0 + r; v[r] = (idx < n) ? cnt[idx] : 0; }
    int s = v[0] + v[1] + v[2] + v[3];
    int x = s;
#pragma unroll
    for (int d = 1; d < 64; d <<= 1){ int t = __shfl_up(x, d, 64); if (lane >= d) x += t; }
    if (lane == 63) wsum[wid] = x;
    __syncthreads();
    if (wid == 0){
      int ws = (lane < 16) ? wsum[lane] : 0;
#pragma unroll
      for (int d = 1; d < 16; d <<= 1){ int t = __shfl_up(ws, d, 64); if (lane >= d) ws += t; }
      if (lane < 16) wsum[lane] = ws;
      if (lane == 15) chunkTot = ws;
    }
    __syncthreads();
    int waveBase = (wid == 0) ? 0 : wsum[wid - 1];
    int run = carry + waveBase + (x - s);
#pragma unroll
    for (int r = 0; r < 4; ++r){ int idx = i0 + r; if (idx < n) off[idx] = run; run += v[r]; }
    __syncthreads();
    if (tid == 0) carry += chunkTot;
    __syncthreads();
  }
  if (tid == 0) off[n] = carry;
}

// ============ CSR fill: NO atomics (slot = off[dst] + rank[e]) =============
__global__ __launch_bounds__(256) void fill_kernel(
    const int* __restrict__ bs, const int* __restrict__ bd,
    const int* __restrict__ isc, const int* __restrict__ idt,
    const int* __restrict__ rank_bel, const int* __restrict__ rank_inc,
    const int* __restrict__ off_bel, const int* __restrict__ off_inc,
    int* __restrict__ csr_bel, int* __restrict__ csr_inc){
  int g = blockIdx.x * blockDim.x + threadIdx.x;
  int s = gridDim.x * blockDim.x;
  for (int e = g; e < NE; e += s){
    csr_bel[off_bel[bd[e]] + rank_bel[e]] = bs[e];
    csr_inc[off_inc[idt[e]] + rank_inc[e]] = isc[e];
  }
}

// ================= bel aggregation (dst = B, 10000 rows) ===================
// P_b[dst] = sum_{e->dst} X[src[e]] * (ss?ss[src]:1); fp32 out, no epilogue.
// one wave per dst row; 32 lanes per edge row (16B/lane), 2 edges/step,
// 64 idx+sc preloaded in one csr shot, wave-uniform 8-edge chunks.
__global__ __launch_bounds__(256) void agg_bel_kernel(
    const u16* __restrict__ X, const float* __restrict__ ss,
    const int* __restrict__ off, const int* __restrict__ csr,
    float* __restrict__ Pf, int nDst){
  int wave = blockIdx.x * 4 + (threadIdx.x >> 6);
  int lane = threadIdx.x & 63;
  if (wave >= nDst) return;
  int b0 = off[wave], b1 = off[wave + 1];
  int deg = b1 - b0;
  int part = lane >> 5;           // 2 parts x 32 lanes
  int cl = lane & 31;
  int c = cl * 8;
  float acc[8];
#pragma unroll
  for (int q = 0; q < 8; ++q) acc[q] = 0.f;
  int idx = 0; float sc = 0.f;
  if (lane < deg){
    idx = csr[b0 + lane];
    sc = ss ? ss[idx] : 1.f;
  }
  int lim = deg < 64 ? deg : 64;
  for (int u = 0; u < lim; u += 8){
    const u16* addr[4]; float w[4];
#pragma unroll
    for (int k = 0; k < 4; ++k){
      int e = u + k * 2 + part;
      int t = e < lim ? e : 0;
      int s0 = __shfl(idx, t, 64);
      float c0 = __shfl(sc, t, 64);
      w[k] = e < lim ? c0 : 0.f;
      addr[k] = X + (size_t)s0 * 256 + c;
    }
    short8 v[4];
#pragma unroll
    for (int k = 0; k < 4; ++k) v[k] = *(const short8*)addr[k];
#pragma unroll
    for (int k = 0; k < 4; ++k)
#pragma unroll
      for (int q = 0; q < 8; ++q) acc[q] += bf2f((u16)v[k][q]) * w[k];
  }
  for (int j = b0 + 64 + part; j < b1; j += 2){
    int s0 = csr[j];
    float c0 = ss ? ss[s0] : 1.f;
    short8 v0 = *(const short8*)(X + (size_t)s0 * 256 + c);
#pragma unroll
    for (int q = 0; q < 8; ++q) acc[q] += bf2f((u16)v0[q]) * c0;
  }
#pragma unroll
  for (int q = 0; q < 8; ++q) acc[q] += __shfl_xor(acc[q], 32, 64);
  if (part == 0){
    f32x4 f0 = {acc[0], acc[1], acc[2], acc[3]};
    f32x4 f1 = {acc[4], acc[5], acc[6], acc[7]};
    __builtin_nontemporal_store(f0, (f32x4*)(Pf + (size_t)wave * 256 + c));
    __builtin_nontemporal_store(f1, (f32x4*)(Pf + (size_t)wave * 256 + c + 4));
  }
}

// ============ merged inc aggregation (dst = A, 50000 rows) =================
// One csr_inc pass over interleaved rows G12[src] = [G1 256 | G2 128] (u16
// stride 384). Full wave per edge: 8B/lane G1-seg + 4B/lane G2-seg.
//   H_a[row]  = relu(sum1*s_ii + b1i) * s_ob   (bf16, pre-scaled for L2 bel agg)
//   out_a[row]=      sum2*s_ii + b2i           (fp32, final output)
__global__ __launch_bounds__(256) void agg_inc2_kernel(
    const u16* __restrict__ G12, const int* __restrict__ off,
    const int* __restrict__ csr,
    const float* __restrict__ s_ii, const float* __restrict__ s_ob,
    const float* __restrict__ b1i, const float* __restrict__ b2i,
    u16* __restrict__ Ha, float* __restrict__ outa){
  int wave = blockIdx.x * 4 + (threadIdx.x >> 6);
  int lane = threadIdx.x & 63;
  if (wave >= NA) return;
  int b0 = off[wave], b1 = off[wave + 1];
  int deg = b1 - b0;
  int c1 = lane * 4;
  int c2 = lane * 2;
  float acc[6];
#pragma unroll
  for (int q = 0; q < 6; ++q) acc[q] = 0.f;
  int idx = 0;
  if (lane < deg) idx = csr[b0 + lane];
  int lim = deg < 64 ? deg : 64;
  for (int u = 0; u < lim; u += 4){
    ushort4 va[4]; ushort2 vb[4]; float w[4];
#pragma unroll
    for (int k = 0; k < 4; ++k){
      int e = u + k;
      int t = e < lim ? e : 0;
      int se = __shfl(idx, t, 64);
      w[k] = e < lim ? 1.f : 0.f;
      const u16* r = G12 + (size_t)se * 384;
      va[k] = *(const ushort4*)(r + c1);
      vb[k] = *(const ushort2*)(r + 256 + c2);
    }
#pragma unroll
    for (int k = 0; k < 4; ++k){
      acc[0] += bf2f(va[k].x) * w[k];
      acc[1] += bf2f(va[k].y) * w[k];
      acc[2] += bf2f(va[k].z) * w[k];
      acc[3] += bf2f(va[k].w) * w[k];
      acc[4] += bf2f(vb[k].x) * w[k];
      acc[5] += bf2f(vb[k].y) * w[k];
    }
  }
  for (int j = b0 + 64; j < b1; ++j){
    int se = csr[j];
    const u16* r = G12 + (size_t)se * 384;
    ushort4 va = *(const ushort4*)(r + c1);
    ushort2 vb = *(const ushort2*)(r + 256 + c2);
    acc[0] += bf2f(va.x); acc[1] += bf2f(va.y);
    acc[2] += bf2f(va.z); acc[3] += bf2f(va.w);
    acc[4] += bf2f(vb.x); acc[5] += bf2f(vb.y);
  }
  float sii = s_ii[wave], sob = s_ob[wave];
  float4 bb1 = *(const float4*)(b1i + c1);
  f32x2 bb2 = *(const f32x2*)(b2i + c2);
  u16x4 o1;
  o1.x = f2bf(fmaxf(acc[0] * sii + bb1.x, 0.f) * sob);
  o1.y = f2bf(fmaxf(acc[1] * sii + bb1.y, 0.f) * sob);
  o1.z = f2bf(fmaxf(acc[2] * sii + bb1.z, 0.f) * sob);
  o1.w = f2bf(fmaxf(acc[3] * sii + bb1.w, 0.f) * sob);
  __builtin_nontemporal_store(o1, (u16x4*)(Ha + (size_t)wave * 256 + c1));
  f32x2 o2 = {acc[4] * sii + bb2.x, acc[5] * sii + bb2.y};
  __builtin_nontemporal_store(o2, (f32x2*)(outa + (size_t)wave * 128 + c2));
}

// ================= GEMM ====================================================
// C[M,N] = relu?( (A[M,256] @ W) * rs[m] + bias[n] ); fp32 via 3-term bf16
// split MFMA; single live accumulator; 4 waves/strip over nt slices.
// Output: fp32 (Cf) or bf16 (C16) at row stride ldC, column offset colOff.
__global__ __launch_bounds__(256) void gemm_kernel(
    const float* __restrict__ A,
    const u16* __restrict__ PWH, const u16* __restrict__ PWL,
    const float* __restrict__ bias, const float* __restrict__ rs,
    float* __restrict__ Cf, u16* __restrict__ C16,
    int M, int nT, int wpsShift, int doRelu, int ldC, int colOff){
  int wave = blockIdx.x * 4 + (threadIdx.x >> 6);
  int lane = threadIdx.x & 63;
  int strips = M >> 4;
  int strip = wave >> wpsShift;
  if (strip >= strips) return;
  int slice = wave & ((1 << wpsShift) - 1);
  int ntPer = nT >> wpsShift;
  int ntStart = slice * ntPer;
  int r16 = lane & 15, quad = lane >> 4;
  int m0 = strip << 4;
  const float* aBase = A + (size_t)(m0 + r16) * 256 + quad * 8;
  short8 ah[8], al[8];
#pragma unroll
  for (int kt = 0; kt < 8; ++kt){
    float4 p0 = *(const float4*)(aBase + kt * 32);
    float4 p1 = *(const float4*)(aBase + kt * 32 + 4);
    float v[8] = {p0.x, p0.y, p0.z, p0.w, p1.x, p1.y, p1.z, p1.w};
    short8 h, l;
#pragma unroll
    for (int j = 0; j < 8; ++j){
      u16 hb = f2bf(v[j]);
      h[j] = (short)hb;
      l[j] = (short)f2bf(v[j] - bf2f(hb));
    }
    ah[kt] = h; al[kt] = l;
  }
  float rscale[4];
#pragma unroll
  for (int r = 0; r < 4; ++r) rscale[r] = rs ? rs[m0 + quad * 4 + r] : 1.f;
  for (int nt = ntStart; nt < ntStart + ntPer; ++nt){
    f32x4 acc = {0.f, 0.f, 0.f, 0.f};
    const u16* bh = PWH + ((size_t)nt * 64 + lane) * 8;
    const u16* bl = PWL + ((size_t)nt * 64 + lane) * 8;
#pragma unroll
    for (int kt = 0; kt < 8; ++kt){
      short8 wh = *(const short8*)(bh + (size_t)kt * nT * 512);
      short8 wl = *(const short8*)(bl + (size_t)kt * nT * 512);
      acc = __builtin_amdgcn_mfma_f32_16x16x32_bf16(ah[kt], wh, acc, 0, 0, 0);
      acc = __builtin_amdgcn_mfma_f32_16x16x32_bf16(al[kt], wh, acc, 0, 0, 0);
      acc = __builtin_amdgcn_mfma_f32_16x16x32_bf16(ah[kt], wl, acc, 0, 0, 0);
    }
    int col = nt * 16 + r16;
    float bv = bias ? bias[col] : 0.f;
#pragma unroll
    for (int r = 0; r < 4; ++r){
      float v = acc[r] * rscale[r] + bv;
      if (doRelu) v = fmaxf(v, 0.f);
      size_t o = (size_t)(m0 + quad * 4 + r) * ldC + colOff + col;
      if (C16) __builtin_nontemporal_store(f2bf(v), C16 + o);
      else     __builtin_nontemporal_store(v, Cf + o);
    }
  }
}

extern "C" void kernel_launch(void* const* d_in, const int* in_sizes, int n_in,
                              void* d_out, int out_size, void* d_ws, size_t ws_size,
                              hipStream_t stream){
  const float* x_a = (const float*)d_in[0];
  const float* x_b = (const float*)d_in[1];
  const float* W1b = (const float*)d_in[2];
  const float* b1b = (const float*)d_in[3];
  const float* W1i = (const float*)d_in[4];
  const float* b1i = (const float*)d_in[5];
  const float* W2b = (const float*)d_in[6];
  const float* b2b = (const float*)d_in[7];
  const float* W2i = (const float*)d_in[8];
  const float* b2i = (const float*)d_in[9];
  const int* bs  = (const int*)d_in[10];
  const int* bd  = (const int*)d_in[11];
  const int* isc = (const int*)d_in[12];
  const int* idt = (const int*)d_in[13];

  char* w = (char*)d_ws;
  size_t o = 0;
  auto take = [&](size_t bytes) -> void* {
    void* p = w + o; o = (o + bytes + 255) & ~(size_t)255; return p;
  };
  int* zint = (int*)take(120000 * sizeof(int));   // 4 degree counters
  int* c_bs = zint, *c_bd = zint + 50000, *c_is = zint + 60000, *c_id = zint + 70000;
  int* rank_bel = (int*)take(NE * sizeof(int));
  int* rank_inc = (int*)take(NE * sizeof(int));
  int* off_bel = (int*)take((NB + 1) * sizeof(int));
  int* off_inc = (int*)take((NA + 1) * sizeof(int));
  int* csr_bel = (int*)take(NE * sizeof(int));
  int* csr_inc = (int*)take(NE * sizeof(int));
  float* s_ob = (float*)take(NA * sizeof(float));  // rsqrt deg_out bel (A)
  float* s_ib = (float*)take(NB * sizeof(float));  // rsqrt deg_in  bel (B)
  float* s_oi = (float*)take(NB * sizeof(float));  // rsqrt deg_out inc (B)
  float* s_ii = (float*)take(NA * sizeof(float));  // rsqrt deg_in  inc (A)
  u16* pwh = (u16*)take(196608 * sizeof(u16));
  u16* pwl = (u16*)take(196608 * sizeof(u16));
  u16* pwh1b = pwh, *pwh1i = pwh + 65536, *pwh2b = pwh + 131072, *pwh2i = pwh + 163840;
  u16* pwl1b = pwl, *pwl1i = pwl + 65536, *pwl2b = pwl + 131072, *pwl2i = pwl + 163840;
  u16* xa16 = (u16*)take((size_t)NA * 256 * sizeof(u16));   // x_a bf16 (unscaled)
  u16* G12  = (u16*)take((size_t)NB * 384 * sizeof(u16));   // [G1 256 | G2 128] bf16
  u16* H_a  = (u16*)take((size_t)NA * 256 * sizeof(u16));   // relu(L1 inc)*s_ob, bf16
  float* P_b = (float*)take((size_t)NB * 256 * sizeof(float)); // bel agg out (reused)
  float* H_b = (float*)take((size_t)NB * 256 * sizeof(float)); // L1 B feats fp32

  float* out_a = (float*)d_out;                     // [NA,128]
  float* out_b = (float*)d_out + (size_t)NA * 128;  // [NB,128]

  // ---- setup ----
  setup0_kernel<<<512, 256, 0, stream>>>(zint, 120000, W1b, W1i, W2b, W2i, pwh, pwl);
  histcvt_kernel<<<HB + CVTB, 256, 0, stream>>>(bs, bd, isc, idt,
                                                c_bs, c_bd, c_is, c_id,
                                                rank_bel, rank_inc, x_a, xa16);
  scan_scales_kernel<<<52, 1024, 0, stream>>>(c_bs, c_bd, c_is, c_id,
                                              off_bel, off_inc,
                                              s_ob, s_ib, s_oi, s_ii);
  fill_kernel<<<1172, 256, 0, stream>>>(bs, bd, isc, idt, rank_bel, rank_inc,
                                        off_bel, off_inc, csr_bel, csr_inc);

  // ---- compute ----
  // G1 = (x_b@W1i)*s_oi  -> G12[:, 0:256) (bf16, stride 384)
  gemm_kernel<<<625, 256, 0, stream>>>(x_b, pwh1i, pwl1i, nullptr, s_oi,
                                       nullptr, G12, NB, 16, 2, 0, 384, 0);
  // P_b = agg_bel(xa16 * s_ob[src])
  agg_bel_kernel<<<2500, 256, 0, stream>>>(xa16, s_ob, off_bel, csr_bel, P_b, NB);
  // H_b = relu((P_b@W1b)*s_ib + b1b)
  gemm_kernel<<<625, 256, 0, stream>>>(P_b, pwh1b, pwl1b, b1b, s_ib,
                                       H_b, nullptr, NB, 16, 2, 1, 256, 0);
  // G2 = (H_b@W2i)*s_oi -> G12[:, 256:384) (bf16, stride 384)
  gemm_kernel<<<625, 256, 0, stream>>>(H_b, pwh2i, pwl2i, nullptr, s_oi,
                                       nullptr, G12, NB, 8, 2, 0, 384, 256);
  // merged inc agg: H_a (bf16, pre-scaled by s_ob) + out_a (fp32, final)
  agg_inc2_kernel<<<12500, 256, 0, stream>>>(G12, off_inc, csr_inc,
                                             s_ii, s_ob, b1i, b2i, H_a, out_a);
  // P_b = agg_bel(H_a)  (H_a already src-scaled)
  agg_bel_kernel<<<2500, 256, 0, stream>>>(H_a, nullptr, off_bel, csr_bel, P_b, NB);
  // out_b = (P_b@W2b)*s_ib + b2b
  gemm_kernel<<<625, 256, 0, stream>>>(P_b, pwh2b, pwl2b, b2b, s_ib,
                                       out_b, nullptr, NB, 8, 2, 0, 128, 0);
}

// Round 10
// 354.873 us; speedup vs baseline: 1.5523x; 1.1535x over previous
//
#include <hip/hip_runtime.h>

// RGCN bipartite, FP32 in/out. Round 10 (9 dispatches):
//   - cvt x_a->bf16 rides in setup0 (hist runs alone at its atomic floor).
//   - fill || G1-gemm fused (block-split; fill is scatter-throughput, tolerant
//     of the gemm's VGPR allocation -- unlike round-6's latency-bound agg).
//   - gemmHG: H_b computed per strip into LDS fp32 (stride 260 vs bank
//     conflicts), barrier, G2 gemm from LDS. H_b never touches global.
//   - aggs unchanged: they sit at the ~45G scattered-lines/s device ceiling
//     (measured invariant across rounds 4/7/8/9).

#define NA 50000
#define NB 10000
#define NE 300000

typedef unsigned short u16;
typedef unsigned int u32;
typedef __attribute__((ext_vector_type(8))) short short8;
typedef __attribute__((ext_vector_type(4))) float f32x4;
typedef __attribute__((ext_vector_type(2))) float f32x2;
typedef __attribute__((ext_vector_type(4))) unsigned short u16x4;

__device__ __forceinline__ float bf2f(u16 h){
  union { u32 u; float f; } x; x.u = ((u32)h) << 16; return x.f;
}
__device__ __forceinline__ u16 f2bf(float f){
  union { float f; u32 u; } x; x.f = f;
  u32 r = (x.u + 0x7FFFu + ((x.u >> 16) & 1u)) >> 16;   // RNE
  return (u16)r;
}

// ====== setup0: zero counters + pack W (hi/lo bf16) + cvt x_a->bf16 ========
__global__ __launch_bounds__(256) void setup0_kernel(
    int* __restrict__ z, int nz,
    const float* __restrict__ W1b, const float* __restrict__ W1i,
    const float* __restrict__ W2b, const float* __restrict__ W2i,
    u16* __restrict__ pwh, u16* __restrict__ pwl,
    const float* __restrict__ xa, u16* __restrict__ xa16){
  int g = blockIdx.x * blockDim.x + threadIdx.x;
  int s = gridDim.x * blockDim.x;
  for (int i = g; i < nz; i += s) z[i] = 0;
  const int total = 65536 + 65536 + 32768 + 32768;
  for (int t = g; t < total; t += s){
    const float* W; int N; int tt;
    if (t < 65536)       { W = W1b; N = 256; tt = t; }
    else if (t < 131072) { W = W1i; N = 256; tt = t - 65536; }
    else if (t < 163840) { W = W2b; N = 128; tt = t - 131072; }
    else                 { W = W2i; N = 128; tt = t - 163840; }
    int j = tt & 7, lane = (tt >> 3) & 63, tile = tt >> 9;
    int nT = N >> 4;
    int nt = tile % nT, kt = tile / nT;
    int k = kt * 32 + ((lane >> 4) << 3) + j;
    int n = nt * 16 + (lane & 15);
    float v = W[k * N + n];
    u16 hi = f2bf(v);
    pwh[t] = hi;
    pwl[t] = f2bf(v - bf2f(hi));
  }
  for (int i = g * 4; i < NA * 256; i += s * 4){
    float4 v = *(const float4*)(xa + i);
    u16x4 o;
    o.x = f2bf(v.x); o.y = f2bf(v.y); o.z = f2bf(v.z); o.w = f2bf(v.w);
    __builtin_nontemporal_store(o, (u16x4*)(xa16 + i));
  }
}

// ================= hist + edge ranks (atomic returns) ======================
__global__ __launch_bounds__(256) void hist_kernel(
    const int* __restrict__ bs, const int* __restrict__ bd,
    const int* __restrict__ isc, const int* __restrict__ idt,
    int* __restrict__ c_bs, int* __restrict__ c_bd,
    int* __restrict__ c_is, int* __restrict__ c_id,
    int* __restrict__ rank_bel, int* __restrict__ rank_inc){
  int g = blockIdx.x * blockDim.x + threadIdx.x;
  int s = gridDim.x * blockDim.x;
  for (int e = g; e < NE; e += s){
    atomicAdd(&c_bs[bs[e]], 1);
    rank_bel[e] = atomicAdd(&c_bd[bd[e]], 1);
    atomicAdd(&c_is[isc[e]], 1);
    rank_inc[e] = atomicAdd(&c_id[idt[e]], 1);
  }
}

// ============ scan (blocks 0,1) + scales (blocks 2..) fused ================
__global__ __launch_bounds__(1024) void scan_scales_kernel(
    const int* __restrict__ c_bs, const int* __restrict__ c_bd,
    const int* __restrict__ c_is, const int* __restrict__ c_id,
    int* __restrict__ off_bel, int* __restrict__ off_inc,
    float* __restrict__ s_ob, float* __restrict__ s_ib,
    float* __restrict__ s_oi, float* __restrict__ s_ii){
  if (blockIdx.x >= 2){
    int g = (blockIdx.x - 2) * blockDim.x + threadIdx.x;
    int s = (gridDim.x - 2) * blockDim.x;
    for (int i = g; i < NA; i += s){
      int a = c_bs[i]; s_ob[i] = rsqrtf((float)(a > 1 ? a : 1));
      int b = c_id[i]; s_ii[i] = rsqrtf((float)(b > 1 ? b : 1));
      if (i < NB){
        int c = c_bd[i]; s_ib[i] = rsqrtf((float)(c > 1 ? c : 1));
        int d = c_is[i]; s_oi[i] = rsqrtf((float)(d > 1 ? d : 1));
      }
    }
    return;
  }
  const int* cnt; int* off; int n;
  if (blockIdx.x == 0){ cnt = c_bd; off = off_bel; n = NB; }
  else                { cnt = c_id; off = off_inc; n = NA; }
  __shared__ int wsum[16];
  __shared__ int carry, chunkTot;
  int tid = threadIdx.x, lane = tid & 63, wid = tid >> 6;
  if (tid == 0) carry = 0;
  __syncthreads();
  for (int base = 0; base < n; base += 4096){
    int i0 = base + tid * 4;
    int v[4];
#pragma unroll
    for (int r = 0; r < 4; ++r){ int idx = i0 + r; v[r] = (idx < n) ? cnt[idx] : 0; }
    int s = v[0] + v[1] + v[2] + v[3];
    int x = s;
#pragma unroll
    for (int d = 1; d < 64; d <<= 1){ int t = __shfl_up(x, d, 64); if (lane >= d) x += t; }
    if (lane == 63) wsum[wid] = x;
    __syncthreads();
    if (wid == 0){
      int ws = (lane < 16) ? wsum[lane] : 0;
#pragma unroll
      for (int d = 1; d < 16; d <<= 1){ int t = __shfl_up(ws, d, 64); if (lane >= d) ws += t; }
      if (lane < 16) wsum[lane] = ws;
      if (lane == 15) chunkTot = ws;
    }
    __syncthreads();
    int waveBase = (wid == 0) ? 0 : wsum[wid - 1];
    int run = carry + waveBase + (x - s);
#pragma unroll
    for (int r = 0; r < 4; ++r){ int idx = i0 + r; if (idx < n) off[idx] = run; run += v[r]; }
    __syncthreads();
    if (tid == 0) carry += chunkTot;
    __syncthreads();
  }
  if (tid == 0) off[n] = carry;
}

// ================= gemm device fn (single live acc, no spills) =============
__device__ __forceinline__ void gemm_dev(int blk, const float* __restrict__ A,
                                         const u16* __restrict__ PWH,
                                         const u16* __restrict__ PWL,
                                         const float* __restrict__ bias,
                                         const float* __restrict__ rs,
                                         float* __restrict__ Cf,
                                         u16* __restrict__ C16,
                                         int M, int nT, int wpsShift,
                                         int doRelu, int ldC, int colOff){
  int wave = blk * 4 + (threadIdx.x >> 6);
  int lane = threadIdx.x & 63;
  int strips = M >> 4;
  int strip = wave >> wpsShift;
  if (strip >= strips) return;
  int slice = wave & ((1 << wpsShift) - 1);
  int ntPer = nT >> wpsShift;
  int ntStart = slice * ntPer;
  int r16 = lane & 15, quad = lane >> 4;
  int m0 = strip << 4;
  const float* aBase = A + (size_t)(m0 + r16) * 256 + quad * 8;
  short8 ah[8], al[8];
#pragma unroll
  for (int kt = 0; kt < 8; ++kt){
    float4 p0 = *(const float4*)(aBase + kt * 32);
    float4 p1 = *(const float4*)(aBase + kt * 32 + 4);
    float v[8] = {p0.x, p0.y, p0.z, p0.w, p1.x, p1.y, p1.z, p1.w};
    short8 h, l;
#pragma unroll
    for (int j = 0; j < 8; ++j){
      u16 hb = f2bf(v[j]);
      h[j] = (short)hb;
      l[j] = (short)f2bf(v[j] - bf2f(hb));
    }
    ah[kt] = h; al[kt] = l;
  }
  float rscale[4];
#pragma unroll
  for (int r = 0; r < 4; ++r) rscale[r] = rs ? rs[m0 + quad * 4 + r] : 1.f;
  for (int nt = ntStart; nt < ntStart + ntPer; ++nt){
    f32x4 acc = {0.f, 0.f, 0.f, 0.f};
    const u16* bh = PWH + ((size_t)nt * 64 + lane) * 8;
    const u16* bl = PWL + ((size_t)nt * 64 + lane) * 8;
#pragma unroll
    for (int kt = 0; kt < 8; ++kt){
      short8 wh = *(const short8*)(bh + (size_t)kt * nT * 512);
      short8 wl = *(const short8*)(bl + (size_t)kt * nT * 512);
      acc = __builtin_amdgcn_mfma_f32_16x16x32_bf16(ah[kt], wh, acc, 0, 0, 0);
      acc = __builtin_amdgcn_mfma_f32_16x16x32_bf16(al[kt], wh, acc, 0, 0, 0);
      acc = __builtin_amdgcn_mfma_f32_16x16x32_bf16(ah[kt], wl, acc, 0, 0, 0);
    }
    int col = nt * 16 + r16;
    float bv = bias ? bias[col] : 0.f;
#pragma unroll
    for (int r = 0; r < 4; ++r){
      float v = acc[r] * rscale[r] + bv;
      if (doRelu) v = fmaxf(v, 0.f);
      size_t o = (size_t)(m0 + quad * 4 + r) * ldC + colOff + col;
      if (C16) __builtin_nontemporal_store(f2bf(v), C16 + o);
      else     __builtin_nontemporal_store(v, Cf + o);
    }
  }
}

// ====== fused: G1 gemm on blocks [0,625) || atomic-free fill on rest =======
__global__ __launch_bounds__(256) void fillg1_kernel(
    const float* __restrict__ xb,
    const u16* __restrict__ WH1i, const u16* __restrict__ WL1i,
    const float* __restrict__ s_oi, u16* __restrict__ G12,
    const int* __restrict__ bs, const int* __restrict__ bd,
    const int* __restrict__ isc, const int* __restrict__ idt,
    const int* __restrict__ rank_bel, const int* __restrict__ rank_inc,
    const int* __restrict__ off_bel, const int* __restrict__ off_inc,
    int* __restrict__ csr_bel, int* __restrict__ csr_inc){
  if (blockIdx.x < 625){
    gemm_dev(blockIdx.x, xb, WH1i, WL1i, nullptr, s_oi,
             nullptr, G12, NB, 16, 2, 0, 384, 0);
  } else {
    int g = (blockIdx.x - 625) * blockDim.x + threadIdx.x;
    int s = (gridDim.x - 625) * blockDim.x;
    for (int e = g; e < NE; e += s){
      csr_bel[off_bel[bd[e]] + rank_bel[e]] = bs[e];
      csr_inc[off_inc[idt[e]] + rank_inc[e]] = isc[e];
    }
  }
}

// ====== gemmHG: H_b strip -> LDS fp32 -> G2 gemm, one block per strip ======
// Phase 1: 4 waves compute H_b[16,256] = relu((P_b@W1b)*s_ib + b1b) into LDS
//          (row stride 260 floats -- breaks the 16-way phase-2 read conflict).
// Phase 2: A-frags from LDS, G2 = (H_b@W2i)*s_oi -> G12 cols [256,384) bf16.
__global__ __launch_bounds__(256) void gemmHG_kernel(
    const float* __restrict__ Pb,
    const u16* __restrict__ WH1b, const u16* __restrict__ WL1b,
    const float* __restrict__ b1b, const float* __restrict__ s_ib,
    const u16* __restrict__ WH2i, const u16* __restrict__ WL2i,
    const float* __restrict__ s_oi, u16* __restrict__ G12){
  __shared__ float Hs[16][260];
  int w = threadIdx.x >> 6;
  int lane = threadIdx.x & 63;
  int r16 = lane & 15, quad = lane >> 4;
  int m0 = blockIdx.x << 4;
  // ---- phase 1 ----
  const float* aBase = Pb + (size_t)(m0 + r16) * 256 + quad * 8;
  short8 ah[8], al[8];
#pragma unroll
  for (int kt = 0; kt < 8; ++kt){
    float4 p0 = *(const float4*)(aBase + kt * 32);
    float4 p1 = *(const float4*)(aBase + kt * 32 + 4);
    float v[8] = {p0.x, p0.y, p0.z, p0.w, p1.x, p1.y, p1.z, p1.w};
    short8 h, l;
#pragma unroll
    for (int j = 0; j < 8; ++j){
      u16 hb = f2bf(v[j]);
      h[j] = (short)hb;
      l[j] = (short)f2bf(v[j] - bf2f(hb));
    }
    ah[kt] = h; al[kt] = l;
  }
  float rs1[4];
#pragma unroll
  for (int r = 0; r < 4; ++r) rs1[r] = s_ib[m0 + quad * 4 + r];
  for (int nt = w * 4; nt < w * 4 + 4; ++nt){
    f32x4 acc = {0.f, 0.f, 0.f, 0.f};
    const u16* bh = WH1b + ((size_t)nt * 64 + lane) * 8;
    const u16* bl = WL1b + ((size_t)nt * 64 + lane) * 8;
#pragma unroll
    for (int kt = 0; kt < 8; ++kt){
      short8 wh = *(const short8*)(bh + (size_t)kt * 16 * 512);
      short8 wl = *(const short8*)(bl + (size_t)kt * 16 * 512);
      acc = __builtin_amdgcn_mfma_f32_16x16x32_bf16(ah[kt], wh, acc, 0, 0, 0);
      acc = __builtin_amdgcn_mfma_f32_16x16x32_bf16(al[kt], wh, acc, 0, 0, 0);
      acc = __builtin_amdgcn_mfma_f32_16x16x32_bf16(ah[kt], wl, acc, 0, 0, 0);
    }
    int col = nt * 16 + r16;
    float bv = b1b[col];
#pragma unroll
    for (int r = 0; r < 4; ++r)
      Hs[quad * 4 + r][col] = fmaxf(acc[r] * rs1[r] + bv, 0.f);
  }
  __syncthreads();
  // ---- phase 2 ----
  short8 ah2[8], al2[8];
#pragma unroll
  for (int kt = 0; kt < 8; ++kt){
    float4 p0 = *(const float4*)&Hs[r16][kt * 32 + quad * 8];
    float4 p1 = *(const float4*)&Hs[r16][kt * 32 + quad * 8 + 4];
    float v[8] = {p0.x, p0.y, p0.z, p0.w, p1.x, p1.y, p1.z, p1.w};
    short8 h, l;
#pragma unroll
    for (int j = 0; j < 8; ++j){
      u16 hb = f2bf(v[j]);
      h[j] = (short)hb;
      l[j] = (short)f2bf(v[j] - bf2f(hb));
    }
    ah2[kt] = h; al2[kt] = l;
  }
  float rs2[4];
#pragma unroll
  for (int r = 0; r < 4; ++r) rs2[r] = s_oi[m0 + quad * 4 + r];
  for (int nt = w * 2; nt < w * 2 + 2; ++nt){
    f32x4 acc = {0.f, 0.f, 0.f, 0.f};
    const u16* bh = WH2i + ((size_t)nt * 64 + lane) * 8;
    const u16* bl = WL2i + ((size_t)nt * 64 + lane) * 8;
#pragma unroll
    for (int kt = 0; kt < 8; ++kt){
      short8 wh = *(const short8*)(bh + (size_t)kt * 8 * 512);
      short8 wl = *(const short8*)(bl + (size_t)kt * 8 * 512);
      acc = __builtin_amdgcn_mfma_f32_16x16x32_bf16(ah2[kt], wh, acc, 0, 0, 0);
      acc = __builtin_amdgcn_mfma_f32_16x16x32_bf16(al2[kt], wh, acc, 0, 0, 0);
      acc = __builtin_amdgcn_mfma_f32_16x16x32_bf16(ah2[kt], wl, acc, 0, 0, 0);
    }
    int col = nt * 16 + r16;
#pragma unroll
    for (int r = 0; r < 4; ++r){
      u16 o = f2bf(acc[r] * rs2[r]);
      __builtin_nontemporal_store(o, G12 + (size_t)(m0 + quad * 4 + r) * 384 + 256 + col);
    }
  }
}

// ================= bel aggregation (dst = B, 10000 rows) ===================
__global__ __launch_bounds__(256) void agg_bel_kernel(
    const u16* __restrict__ X, const float* __restrict__ ss,
    const int* __restrict__ off, const int* __restrict__ csr,
    float* __restrict__ Pf, int nDst){
  int wave = blockIdx.x * 4 + (threadIdx.x >> 6);
  int lane = threadIdx.x & 63;
  if (wave >= nDst) return;
  int b0 = off[wave], b1 = off[wave + 1];
  int deg = b1 - b0;
  int part = lane >> 5;
  int cl = lane & 31;
  int c = cl * 8;
  float acc[8];
#pragma unroll
  for (int q = 0; q < 8; ++q) acc[q] = 0.f;
  int idx = 0; float sc = 0.f;
  if (lane < deg){
    idx = csr[b0 + lane];
    sc = ss ? ss[idx] : 1.f;
  }
  int lim = deg < 64 ? deg : 64;
  for (int u = 0; u < lim; u += 8){
    const u16* addr[4]; float w[4];
#pragma unroll
    for (int k = 0; k < 4; ++k){
      int e = u + k * 2 + part;
      int t = e < lim ? e : 0;
      int s0 = __shfl(idx, t, 64);
      float c0 = __shfl(sc, t, 64);
      w[k] = e < lim ? c0 : 0.f;
      addr[k] = X + (size_t)s0 * 256 + c;
    }
    short8 v[4];
#pragma unroll
    for (int k = 0; k < 4; ++k) v[k] = *(const short8*)addr[k];
#pragma unroll
    for (int k = 0; k < 4; ++k)
#pragma unroll
      for (int q = 0; q < 8; ++q) acc[q] += bf2f((u16)v[k][q]) * w[k];
  }
  for (int j = b0 + 64 + part; j < b1; j += 2){
    int s0 = csr[j];
    float c0 = ss ? ss[s0] : 1.f;
    short8 v0 = *(const short8*)(X + (size_t)s0 * 256 + c);
#pragma unroll
    for (int q = 0; q < 8; ++q) acc[q] += bf2f((u16)v0[q]) * c0;
  }
#pragma unroll
  for (int q = 0; q < 8; ++q) acc[q] += __shfl_xor(acc[q], 32, 64);
  if (part == 0){
    f32x4 f0 = {acc[0], acc[1], acc[2], acc[3]};
    f32x4 f1 = {acc[4], acc[5], acc[6], acc[7]};
    __builtin_nontemporal_store(f0, (f32x4*)(Pf + (size_t)wave * 256 + c));
    __builtin_nontemporal_store(f1, (f32x4*)(Pf + (size_t)wave * 256 + c + 4));
  }
}

// ============ merged inc aggregation (dst = A, 50000 rows) =================
__global__ __launch_bounds__(256) void agg_inc2_kernel(
    const u16* __restrict__ G12, const int* __restrict__ off,
    const int* __restrict__ csr,
    const float* __restrict__ s_ii, const float* __restrict__ s_ob,
    const float* __restrict__ b1i, const float* __restrict__ b2i,
    u16* __restrict__ Ha, float* __restrict__ outa){
  int wave = blockIdx.x * 4 + (threadIdx.x >> 6);
  int lane = threadIdx.x & 63;
  if (wave >= NA) return;
  int b0 = off[wave], b1 = off[wave + 1];
  int deg = b1 - b0;
  int c1 = lane * 4;
  int c2 = lane * 2;
  float acc[6];
#pragma unroll
  for (int q = 0; q < 6; ++q) acc[q] = 0.f;
  int idx = 0;
  if (lane < deg) idx = csr[b0 + lane];
  int lim = deg < 64 ? deg : 64;
  for (int u = 0; u < lim; u += 4){
    ushort4 va[4]; ushort2 vb[4]; float w[4];
#pragma unroll
    for (int k = 0; k < 4; ++k){
      int e = u + k;
      int t = e < lim ? e : 0;
      int se = __shfl(idx, t, 64);
      w[k] = e < lim ? 1.f : 0.f;
      const u16* r = G12 + (size_t)se * 384;
      va[k] = *(const ushort4*)(r + c1);
      vb[k] = *(const ushort2*)(r + 256 + c2);
    }
#pragma unroll
    for (int k = 0; k < 4; ++k){
      acc[0] += bf2f(va[k].x) * w[k];
      acc[1] += bf2f(va[k].y) * w[k];
      acc[2] += bf2f(va[k].z) * w[k];
      acc[3] += bf2f(va[k].w) * w[k];
      acc[4] += bf2f(vb[k].x) * w[k];
      acc[5] += bf2f(vb[k].y) * w[k];
    }
  }
  for (int j = b0 + 64; j < b1; ++j){
    int se = csr[j];
    const u16* r = G12 + (size_t)se * 384;
    ushort4 va = *(const ushort4*)(r + c1);
    ushort2 vb = *(const ushort2*)(r + 256 + c2);
    acc[0] += bf2f(va.x); acc[1] += bf2f(va.y);
    acc[2] += bf2f(va.z); acc[3] += bf2f(va.w);
    acc[4] += bf2f(vb.x); acc[5] += bf2f(vb.y);
  }
  float sii = s_ii[wave], sob = s_ob[wave];
  float4 bb1 = *(const float4*)(b1i + c1);
  f32x2 bb2 = *(const f32x2*)(b2i + c2);
  u16x4 o1;
  o1.x = f2bf(fmaxf(acc[0] * sii + bb1.x, 0.f) * sob);
  o1.y = f2bf(fmaxf(acc[1] * sii + bb1.y, 0.f) * sob);
  o1.z = f2bf(fmaxf(acc[2] * sii + bb1.z, 0.f) * sob);
  o1.w = f2bf(fmaxf(acc[3] * sii + bb1.w, 0.f) * sob);
  __builtin_nontemporal_store(o1, (u16x4*)(Ha + (size_t)wave * 256 + c1));
  f32x2 o2 = {acc[4] * sii + bb2.x, acc[5] * sii + bb2.y};
  __builtin_nontemporal_store(o2, (f32x2*)(outa + (size_t)wave * 128 + c2));
}

// ================= standalone GEMM (for out_b) =============================
__global__ __launch_bounds__(256) void gemm_kernel(
    const float* __restrict__ A,
    const u16* __restrict__ PWH, const u16* __restrict__ PWL,
    const float* __restrict__ bias, const float* __restrict__ rs,
    float* __restrict__ Cf, u16* __restrict__ C16,
    int M, int nT, int wpsShift, int doRelu, int ldC, int colOff){
  gemm_dev(blockIdx.x, A, PWH, PWL, bias, rs, Cf, C16,
           M, nT, wpsShift, doRelu, ldC, colOff);
}

extern "C" void kernel_launch(void* const* d_in, const int* in_sizes, int n_in,
                              void* d_out, int out_size, void* d_ws, size_t ws_size,
                              hipStream_t stream){
  const float* x_a = (const float*)d_in[0];
  const float* x_b = (const float*)d_in[1];
  const float* W1b = (const float*)d_in[2];
  const float* b1b = (const float*)d_in[3];
  const float* W1i = (const float*)d_in[4];
  const float* b1i = (const float*)d_in[5];
  const float* W2b = (const float*)d_in[6];
  const float* b2b = (const float*)d_in[7];
  const float* W2i = (const float*)d_in[8];
  const float* b2i = (const float*)d_in[9];
  const int* bs  = (const int*)d_in[10];
  const int* bd  = (const int*)d_in[11];
  const int* isc = (const int*)d_in[12];
  const int* idt = (const int*)d_in[13];

  char* w = (char*)d_ws;
  size_t o = 0;
  auto take = [&](size_t bytes) -> void* {
    void* p = w + o; o = (o + bytes + 255) & ~(size_t)255; return p;
  };
  int* zint = (int*)take(120000 * sizeof(int));   // 4 degree counters
  int* c_bs = zint, *c_bd = zint + 50000, *c_is = zint + 60000, *c_id = zint + 70000;
  int* rank_bel = (int*)take(NE * sizeof(int));
  int* rank_inc = (int*)take(NE * sizeof(int));
  int* off_bel = (int*)take((NB + 1) * sizeof(int));
  int* off_inc = (int*)take((NA + 1) * sizeof(int));
  int* csr_bel = (int*)take(NE * sizeof(int));
  int* csr_inc = (int*)take(NE * sizeof(int));
  float* s_ob = (float*)take(NA * sizeof(float));
  float* s_ib = (float*)take(NB * sizeof(float));
  float* s_oi = (float*)take(NB * sizeof(float));
  float* s_ii = (float*)take(NA * sizeof(float));
  u16* pwh = (u16*)take(196608 * sizeof(u16));
  u16* pwl = (u16*)take(196608 * sizeof(u16));
  u16* pwh1b = pwh, *pwh1i = pwh + 65536, *pwh2b = pwh + 131072, *pwh2i = pwh + 163840;
  u16* pwl1b = pwl, *pwl1i = pwl + 65536, *pwl2b = pwl + 131072, *pwl2i = pwl + 163840;
  u16* xa16 = (u16*)take((size_t)NA * 256 * sizeof(u16));   // x_a bf16 (unscaled)
  u16* G12  = (u16*)take((size_t)NB * 384 * sizeof(u16));   // [G1 256 | G2 128] bf16
  u16* H_a  = (u16*)take((size_t)NA * 256 * sizeof(u16));   // relu(L1 inc)*s_ob, bf16
  float* P_b = (float*)take((size_t)NB * 256 * sizeof(float)); // bel agg out (reused)

  float* out_a = (float*)d_out;                     // [NA,128]
  float* out_b = (float*)d_out + (size_t)NA * 128;  // [NB,128]

  // ---- setup ----
  setup0_kernel<<<1024, 256, 0, stream>>>(zint, 120000, W1b, W1i, W2b, W2i,
                                          pwh, pwl, x_a, xa16);
  hist_kernel<<<1172, 256, 0, stream>>>(bs, bd, isc, idt,
                                        c_bs, c_bd, c_is, c_id,
                                        rank_bel, rank_inc);
  scan_scales_kernel<<<52, 1024, 0, stream>>>(c_bs, c_bd, c_is, c_id,
                                              off_bel, off_inc,
                                              s_ob, s_ib, s_oi, s_ii);
  // ---- compute ----
  // [G1 = (x_b@W1i)*s_oi -> G12 cols 0..255]  ||  [atomic-free CSR fill]
  fillg1_kernel<<<625 + 1172, 256, 0, stream>>>(x_b, pwh1i, pwl1i, s_oi, G12,
                                                bs, bd, isc, idt,
                                                rank_bel, rank_inc,
                                                off_bel, off_inc,
                                                csr_bel, csr_inc);
  // P_b = agg_bel(xa16 * s_ob[src])
  agg_bel_kernel<<<2500, 256, 0, stream>>>(xa16, s_ob, off_bel, csr_bel, P_b, NB);
  // H_b (LDS-only) = relu((P_b@W1b)*s_ib+b1b); G2 = (H_b@W2i)*s_oi -> G12 cols 256..
  gemmHG_kernel<<<625, 256, 0, stream>>>(P_b, pwh1b, pwl1b, b1b, s_ib,
                                         pwh2i, pwl2i, s_oi, G12);
  // merged inc agg: H_a (bf16, pre-scaled by s_ob) + out_a (fp32, final)
  agg_inc2_kernel<<<12500, 256, 0, stream>>>(G12, off_inc, csr_inc,
                                             s_ii, s_ob, b1i, b2i, H_a, out_a);
  // P_b = agg_bel(H_a)  (H_a already src-scaled)
  agg_bel_kernel<<<2500, 256, 0, stream>>>(H_a, nullptr, off_bel, csr_bel, P_b, NB);
  // out_b = (P_b@W2b)*s_ib + b2b
  gemm_kernel<<<625, 256, 0, stream>>>(P_b, pwh2b, pwl2b, b2b, s_ib,
                                       out_b, nullptr, NB, 8, 2, 0, 128, 0);
}

// Round 11
// 348.726 us; speedup vs baseline: 1.5797x; 1.0176x over previous
//
#include <hip/hip_runtime.h>

// RGCN bipartite, FP32 in/out. Round 11 (9 dispatches):
//   - MEGA dispatch: [G1 gemm | hist+ranks | pack W1b/W2b/W2i | cvt x_a->bf16]
//     block-range fused -- hist is atomic-bound (0.2% VALU), everything else
//     rides under its 60us. VGPR 88 shared: hist needs ~18 waves/CU, has 20.
//   - pre kernel (3us): zero counters + pack W1i (so G1 gemm operand is not
//     raced by the in-dispatch pack).
//   - G1/G2 stored UNSCALED; s_oi[src] applied as gather weight in agg_inc2
//     (scattered 4B scale load per lane per wave -- proven free in round 7).
//   - fill standalone (atomic-free, slot = off[dst]+rank[e]).
//   - gemmHG (H_b LDS-only), merged inc agg, nt stores: carried from round 10.

#define NA 50000
#define NB 10000
#define NE 300000
#define GB 625      // mega: gemm blocks
#define HB 1172     // mega: hist blocks
#define PB 64       // mega: pack blocks
#define CB 300      // mega: cvt blocks

typedef unsigned short u16;
typedef unsigned int u32;
typedef __attribute__((ext_vector_type(8))) short short8;
typedef __attribute__((ext_vector_type(4))) float f32x4;
typedef __attribute__((ext_vector_type(2))) float f32x2;
typedef __attribute__((ext_vector_type(4))) unsigned short u16x4;

__device__ __forceinline__ float bf2f(u16 h){
  union { u32 u; float f; } x; x.u = ((u32)h) << 16; return x.f;
}
__device__ __forceinline__ u16 f2bf(float f){
  union { float f; u32 u; } x; x.f = f;
  u32 r = (x.u + 0x7FFFu + ((x.u >> 16) & 1u)) >> 16;   // RNE
  return (u16)r;
}

// pack element t of the global layout [W1b 64k][W1i 64k][W2b 32k][W2i 32k]
__device__ __forceinline__ void pack_elem(int t,
    const float* __restrict__ W1b, const float* __restrict__ W1i,
    const float* __restrict__ W2b, const float* __restrict__ W2i,
    u16* __restrict__ pwh, u16* __restrict__ pwl){
  const float* W; int N; int tt;
  if (t < 65536)       { W = W1b; N = 256; tt = t; }
  else if (t < 131072) { W = W1i; N = 256; tt = t - 65536; }
  else if (t < 163840) { W = W2b; N = 128; tt = t - 131072; }
  else                 { W = W2i; N = 128; tt = t - 163840; }
  int j = tt & 7, lane = (tt >> 3) & 63, tile = tt >> 9;
  int nT = N >> 4;
  int nt = tile % nT, kt = tile / nT;
  int k = kt * 32 + ((lane >> 4) << 3) + j;
  int n = nt * 16 + (lane & 15);
  float v = W[k * N + n];
  u16 hi = f2bf(v);
  pwh[t] = hi;
  pwl[t] = f2bf(v - bf2f(hi));
}

// ====== pre: zero counters + pack W1i only (G1 gemm operand) ===============
__global__ __launch_bounds__(256) void pre_kernel(
    int* __restrict__ z, int nz, const float* __restrict__ W1i,
    u16* __restrict__ pwh, u16* __restrict__ pwl){
  int g = blockIdx.x * blockDim.x + threadIdx.x;
  int s = gridDim.x * blockDim.x;
  for (int i = g; i < nz; i += s) z[i] = 0;
  for (int t = g; t < 65536; t += s)
    pack_elem(65536 + t, nullptr, W1i, nullptr, nullptr, pwh, pwl);
}

// ================= gemm device fn (single live acc, no spills) =============
__device__ __forceinline__ void gemm_dev(int blk, const float* __restrict__ A,
                                         const u16* __restrict__ PWH,
                                         const u16* __restrict__ PWL,
                                         const float* __restrict__ bias,
                                         const float* __restrict__ rs,
                                         float* __restrict__ Cf,
                                         u16* __restrict__ C16,
                                         int M, int nT, int wpsShift,
                                         int doRelu, int ldC, int colOff){
  int wave = blk * 4 + (threadIdx.x >> 6);
  int lane = threadIdx.x & 63;
  int strips = M >> 4;
  int strip = wave >> wpsShift;
  if (strip >= strips) return;
  int slice = wave & ((1 << wpsShift) - 1);
  int ntPer = nT >> wpsShift;
  int ntStart = slice * ntPer;
  int r16 = lane & 15, quad = lane >> 4;
  int m0 = strip << 4;
  const float* aBase = A + (size_t)(m0 + r16) * 256 + quad * 8;
  short8 ah[8], al[8];
#pragma unroll
  for (int kt = 0; kt < 8; ++kt){
    float4 p0 = *(const float4*)(aBase + kt * 32);
    float4 p1 = *(const float4*)(aBase + kt * 32 + 4);
    float v[8] = {p0.x, p0.y, p0.z, p0.w, p1.x, p1.y, p1.z, p1.w};
    short8 h, l;
#pragma unroll
    for (int j = 0; j < 8; ++j){
      u16 hb = f2bf(v[j]);
      h[j] = (short)hb;
      l[j] = (short)f2bf(v[j] - bf2f(hb));
    }
    ah[kt] = h; al[kt] = l;
  }
  float rscale[4];
#pragma unroll
  for (int r = 0; r < 4; ++r) rscale[r] = rs ? rs[m0 + quad * 4 + r] : 1.f;
  for (int nt = ntStart; nt < ntStart + ntPer; ++nt){
    f32x4 acc = {0.f, 0.f, 0.f, 0.f};
    const u16* bh = PWH + ((size_t)nt * 64 + lane) * 8;
    const u16* bl = PWL + ((size_t)nt * 64 + lane) * 8;
#pragma unroll
    for (int kt = 0; kt < 8; ++kt){
      short8 wh = *(const short8*)(bh + (size_t)kt * nT * 512);
      short8 wl = *(const short8*)(bl + (size_t)kt * nT * 512);
      acc = __builtin_amdgcn_mfma_f32_16x16x32_bf16(ah[kt], wh, acc, 0, 0, 0);
      acc = __builtin_amdgcn_mfma_f32_16x16x32_bf16(al[kt], wh, acc, 0, 0, 0);
      acc = __builtin_amdgcn_mfma_f32_16x16x32_bf16(ah[kt], wl, acc, 0, 0, 0);
    }
    int col = nt * 16 + r16;
    float bv = bias ? bias[col] : 0.f;
#pragma unroll
    for (int r = 0; r < 4; ++r){
      float v = acc[r] * rscale[r] + bv;
      if (doRelu) v = fmaxf(v, 0.f);
      size_t o = (size_t)(m0 + quad * 4 + r) * ldC + colOff + col;
      if (C16) __builtin_nontemporal_store(f2bf(v), C16 + o);
      else     __builtin_nontemporal_store(v, Cf + o);
    }
  }
}

// ====== MEGA: [G1 gemm | hist+ranks | pack rest | cvt x_a] block-split =====
__global__ __launch_bounds__(256) void mega_kernel(
    const float* __restrict__ xb,
    const u16* __restrict__ WH1i, const u16* __restrict__ WL1i,
    u16* __restrict__ G12,
    const int* __restrict__ bs, const int* __restrict__ bd,
    const int* __restrict__ isc, const int* __restrict__ idt,
    int* __restrict__ c_bs, int* __restrict__ c_bd,
    int* __restrict__ c_is, int* __restrict__ c_id,
    int* __restrict__ rank_bel, int* __restrict__ rank_inc,
    const float* __restrict__ W1b, const float* __restrict__ W2b,
    const float* __restrict__ W2i,
    u16* __restrict__ pwh, u16* __restrict__ pwl,
    const float* __restrict__ xa, u16* __restrict__ xa16){
  int blk = blockIdx.x;
  if (blk < GB){
    // G1 = x_b @ W1i (UNSCALED; s_oi applied at gather) -> G12 cols [0,256)
    gemm_dev(blk, xb, WH1i, WL1i, nullptr, nullptr,
             nullptr, G12, NB, 16, 2, 0, 384, 0);
  } else if (blk < GB + HB){
    int g = (blk - GB) * blockDim.x + threadIdx.x;
    int s = HB * blockDim.x;
    for (int e = g; e < NE; e += s){
      atomicAdd(&c_bs[bs[e]], 1);
      rank_bel[e] = atomicAdd(&c_bd[bd[e]], 1);
      atomicAdd(&c_is[isc[e]], 1);
      rank_inc[e] = atomicAdd(&c_id[idt[e]], 1);
    }
  } else if (blk < GB + HB + PB){
    int g = (blk - GB - HB) * blockDim.x + threadIdx.x;
    int s = PB * blockDim.x;
    for (int v = g; v < 131072; v += s){
      int t = v < 65536 ? v : v + 65536;   // skip W1i range (packed in pre)
      pack_elem(t, W1b, nullptr, W2b, W2i, pwh, pwl);
    }
  } else {
    int g = ((blk - GB - HB - PB) * blockDim.x + threadIdx.x) * 4;
    int s = CB * blockDim.x * 4;
    for (int i = g; i < NA * 256; i += s){
      float4 v = *(const float4*)(xa + i);
      u16x4 o;
      o.x = f2bf(v.x); o.y = f2bf(v.y); o.z = f2bf(v.z); o.w = f2bf(v.w);
      __builtin_nontemporal_store(o, (u16x4*)(xa16 + i));
    }
  }
}

// ============ scan (blocks 0,1) + scales (blocks 2..) fused ================
__global__ __launch_bounds__(1024) void scan_scales_kernel(
    const int* __restrict__ c_bs, const int* __restrict__ c_bd,
    const int* __restrict__ c_is, const int* __restrict__ c_id,
    int* __restrict__ off_bel, int* __restrict__ off_inc,
    float* __restrict__ s_ob, float* __restrict__ s_ib,
    float* __restrict__ s_oi, float* __restrict__ s_ii){
  if (blockIdx.x >= 2){
    int g = (blockIdx.x - 2) * blockDim.x + threadIdx.x;
    int s = (gridDim.x - 2) * blockDim.x;
    for (int i = g; i < NA; i += s){
      int a = c_bs[i]; s_ob[i] = rsqrtf((float)(a > 1 ? a : 1));
      int b = c_id[i]; s_ii[i] = rsqrtf((float)(b > 1 ? b : 1));
      if (i < NB){
        int c = c_bd[i]; s_ib[i] = rsqrtf((float)(c > 1 ? c : 1));
        int d = c_is[i]; s_oi[i] = rsqrtf((float)(d > 1 ? d : 1));
      }
    }
    return;
  }
  const int* cnt; int* off; int n;
  if (blockIdx.x == 0){ cnt = c_bd; off = off_bel; n = NB; }
  else                { cnt = c_id; off = off_inc; n = NA; }
  __shared__ int wsum[16];
  __shared__ int carry, chunkTot;
  int tid = threadIdx.x, lane = tid & 63, wid = tid >> 6;
  if (tid == 0) carry = 0;
  __syncthreads();
  for (int base = 0; base < n; base += 4096){
    int i0 = base + tid * 4;
    int v[4];
#pragma unroll
    for (int r = 0; r < 4; ++r){ int idx = i0 + r; v[r] = (idx < n) ? cnt[idx] : 0; }
    int s = v[0] + v[1] + v[2] + v[3];
    int x = s;
#pragma unroll
    for (int d = 1; d < 64; d <<= 1){ int t = __shfl_up(x, d, 64); if (lane >= d) x += t; }
    if (lane == 63) wsum[wid] = x;
    __syncthreads();
    if (wid == 0){
      int ws = (lane < 16) ? wsum[lane] : 0;
#pragma unroll
      for (int d = 1; d < 16; d <<= 1){ int t = __shfl_up(ws, d, 64); if (lane >= d) ws += t; }
      if (lane < 16) wsum[lane] = ws;
      if (lane == 15) chunkTot = ws;
    }
    __syncthreads();
    int waveBase = (wid == 0) ? 0 : wsum[wid - 1];
    int run = carry + waveBase + (x - s);
#pragma unroll
    for (int r = 0; r < 4; ++r){ int idx = i0 + r; if (idx < n) off[idx] = run; run += v[r]; }
    __syncthreads();
    if (tid == 0) carry += chunkTot;
    __syncthreads();
  }
  if (tid == 0) off[n] = carry;
}

// ============ CSR fill: NO atomics (slot = off[dst] + rank[e]) =============
__global__ __launch_bounds__(256) void fill_kernel(
    const int* __restrict__ bs, const int* __restrict__ bd,
    const int* __restrict__ isc, const int* __restrict__ idt,
    const int* __restrict__ rank_bel, const int* __restrict__ rank_inc,
    const int* __restrict__ off_bel, const int* __restrict__ off_inc,
    int* __restrict__ csr_bel, int* __restrict__ csr_inc){
  int g = blockIdx.x * blockDim.x + threadIdx.x;
  int s = gridDim.x * blockDim.x;
  for (int e = g; e < NE; e += s){
    csr_bel[off_bel[bd[e]] + rank_bel[e]] = bs[e];
    csr_inc[off_inc[idt[e]] + rank_inc[e]] = isc[e];
  }
}

// ====== gemmHG: H_b strip -> LDS fp32 -> G2 gemm (UNSCALED), per strip =====
__global__ __launch_bounds__(256) void gemmHG_kernel(
    const float* __restrict__ Pb,
    const u16* __restrict__ WH1b, const u16* __restrict__ WL1b,
    const float* __restrict__ b1b, const float* __restrict__ s_ib,
    const u16* __restrict__ WH2i, const u16* __restrict__ WL2i,
    u16* __restrict__ G12){
  __shared__ float Hs[16][260];
  int w = threadIdx.x >> 6;
  int lane = threadIdx.x & 63;
  int r16 = lane & 15, quad = lane >> 4;
  int m0 = blockIdx.x << 4;
  // ---- phase 1: H_b = relu((P_b@W1b)*s_ib + b1b) into LDS ----
  const float* aBase = Pb + (size_t)(m0 + r16) * 256 + quad * 8;
  short8 ah[8], al[8];
#pragma unroll
  for (int kt = 0; kt < 8; ++kt){
    float4 p0 = *(const float4*)(aBase + kt * 32);
    float4 p1 = *(const float4*)(aBase + kt * 32 + 4);
    float v[8] = {p0.x, p0.y, p0.z, p0.w, p1.x, p1.y, p1.z, p1.w};
    short8 h, l;
#pragma unroll
    for (int j = 0; j < 8; ++j){
      u16 hb = f2bf(v[j]);
      h[j] = (short)hb;
      l[j] = (short)f2bf(v[j] - bf2f(hb));
    }
    ah[kt] = h; al[kt] = l;
  }
  float rs1[4];
#pragma unroll
  for (int r = 0; r < 4; ++r) rs1[r] = s_ib[m0 + quad * 4 + r];
  for (int nt = w * 4; nt < w * 4 + 4; ++nt){
    f32x4 acc = {0.f, 0.f, 0.f, 0.f};
    const u16* bh = WH1b + ((size_t)nt * 64 + lane) * 8;
    const u16* bl = WL1b + ((size_t)nt * 64 + lane) * 8;
#pragma unroll
    for (int kt = 0; kt < 8; ++kt){
      short8 wh = *(const short8*)(bh + (size_t)kt * 16 * 512);
      short8 wl = *(const short8*)(bl + (size_t)kt * 16 * 512);
      acc = __builtin_amdgcn_mfma_f32_16x16x32_bf16(ah[kt], wh, acc, 0, 0, 0);
      acc = __builtin_amdgcn_mfma_f32_16x16x32_bf16(al[kt], wh, acc, 0, 0, 0);
      acc = __builtin_amdgcn_mfma_f32_16x16x32_bf16(ah[kt], wl, acc, 0, 0, 0);
    }
    int col = nt * 16 + r16;
    float bv = b1b[col];
#pragma unroll
    for (int r = 0; r < 4; ++r)
      Hs[quad * 4 + r][col] = fmaxf(acc[r] * rs1[r] + bv, 0.f);
  }
  __syncthreads();
  // ---- phase 2: G2 = H_b @ W2i (UNSCALED) -> G12 cols [256,384) ----
  short8 ah2[8], al2[8];
#pragma unroll
  for (int kt = 0; kt < 8; ++kt){
    float4 p0 = *(const float4*)&Hs[r16][kt * 32 + quad * 8];
    float4 p1 = *(const float4*)&Hs[r16][kt * 32 + quad * 8 + 4];
    float v[8] = {p0.x, p0.y, p0.z, p0.w, p1.x, p1.y, p1.z, p1.w};
    short8 h, l;
#pragma unroll
    for (int j = 0; j < 8; ++j){
      u16 hb = f2bf(v[j]);
      h[j] = (short)hb;
      l[j] = (short)f2bf(v[j] - bf2f(hb));
    }
    ah2[kt] = h; al2[kt] = l;
  }
  for (int nt = w * 2; nt < w * 2 + 2; ++nt){
    f32x4 acc = {0.f, 0.f, 0.f, 0.f};
    const u16* bh = WH2i + ((size_t)nt * 64 + lane) * 8;
    const u16* bl = WL2i + ((size_t)nt * 64 + lane) * 8;
#pragma unroll
    for (int kt = 0; kt < 8; ++kt){
      short8 wh = *(const short8*)(bh + (size_t)kt * 8 * 512);
      short8 wl = *(const short8*)(bl + (size_t)kt * 8 * 512);
      acc = __builtin_amdgcn_mfma_f32_16x16x32_bf16(ah2[kt], wh, acc, 0, 0, 0);
      acc = __builtin_amdgcn_mfma_f32_16x16x32_bf16(al2[kt], wh, acc, 0, 0, 0);
      acc = __builtin_amdgcn_mfma_f32_16x16x32_bf16(ah2[kt], wl, acc, 0, 0, 0);
    }
    int col = nt * 16 + r16;
#pragma unroll
    for (int r = 0; r < 4; ++r){
      u16 o = f2bf(acc[r]);
      __builtin_nontemporal_store(o, G12 + (size_t)(m0 + quad * 4 + r) * 384 + 256 + col);
    }
  }
}

// ================= bel aggregation (dst = B, 10000 rows) ===================
__global__ __launch_bounds__(256) void agg_bel_kernel(
    const u16* __restrict__ X, const float* __restrict__ ss,
    const int* __restrict__ off, const int* __restrict__ csr,
    float* __restrict__ Pf, int nDst){
  int wave = blockIdx.x * 4 + (threadIdx.x >> 6);
  int lane = threadIdx.x & 63;
  if (wave >= nDst) return;
  int b0 = off[wave], b1 = off[wave + 1];
  int deg = b1 - b0;
  int part = lane >> 5;
  int cl = lane & 31;
  int c = cl * 8;
  float acc[8];
#pragma unroll
  for (int q = 0; q < 8; ++q) acc[q] = 0.f;
  int idx = 0; float sc = 0.f;
  if (lane < deg){
    idx = csr[b0 + lane];
    sc = ss ? ss[idx] : 1.f;
  }
  int lim = deg < 64 ? deg : 64;
  for (int u = 0; u < lim; u += 8){
    const u16* addr[4]; float w[4];
#pragma unroll
    for (int k = 0; k < 4; ++k){
      int e = u + k * 2 + part;
      int t = e < lim ? e : 0;
      int s0 = __shfl(idx, t, 64);
      float c0 = __shfl(sc, t, 64);
      w[k] = e < lim ? c0 : 0.f;
      addr[k] = X + (size_t)s0 * 256 + c;
    }
    short8 v[4];
#pragma unroll
    for (int k = 0; k < 4; ++k) v[k] = *(const short8*)addr[k];
#pragma unroll
    for (int k = 0; k < 4; ++k)
#pragma unroll
      for (int q = 0; q < 8; ++q) acc[q] += bf2f((u16)v[k][q]) * w[k];
  }
  for (int j = b0 + 64 + part; j < b1; j += 2){
    int s0 = csr[j];
    float c0 = ss ? ss[s0] : 1.f;
    short8 v0 = *(const short8*)(X + (size_t)s0 * 256 + c);
#pragma unroll
    for (int q = 0; q < 8; ++q) acc[q] += bf2f((u16)v0[q]) * c0;
  }
#pragma unroll
  for (int q = 0; q < 8; ++q) acc[q] += __shfl_xor(acc[q], 32, 64);
  if (part == 0){
    f32x4 f0 = {acc[0], acc[1], acc[2], acc[3]};
    f32x4 f1 = {acc[4], acc[5], acc[6], acc[7]};
    __builtin_nontemporal_store(f0, (f32x4*)(Pf + (size_t)wave * 256 + c));
    __builtin_nontemporal_store(f1, (f32x4*)(Pf + (size_t)wave * 256 + c + 4));
  }
}

// ============ merged inc aggregation (dst = A, 50000 rows) =================
// gather weight = s_oi[src] (G1/G2 stored unscaled); epilogues per segment.
__global__ __launch_bounds__(256) void agg_inc2_kernel(
    const u16* __restrict__ G12, const int* __restrict__ off,
    const int* __restrict__ csr, const float* __restrict__ s_oi,
    const float* __restrict__ s_ii, const float* __restrict__ s_ob,
    const float* __restrict__ b1i, const float* __restrict__ b2i,
    u16* __restrict__ Ha, float* __restrict__ outa){
  int wave = blockIdx.x * 4 + (threadIdx.x >> 6);
  int lane = threadIdx.x & 63;
  if (wave >= NA) return;
  int b0 = off[wave], b1 = off[wave + 1];
  int deg = b1 - b0;
  int c1 = lane * 4;
  int c2 = lane * 2;
  float acc[6];
#pragma unroll
  for (int q = 0; q < 6; ++q) acc[q] = 0.f;
  int idx = 0; float sc = 0.f;
  if (lane < deg){
    idx = csr[b0 + lane];
    sc = s_oi[idx];
  }
  int lim = deg < 64 ? deg : 64;
  for (int u = 0; u < lim; u += 4){
    ushort4 va[4]; ushort2 vb[4]; float w[4];
#pragma unroll
    for (int k = 0; k < 4; ++k){
      int e = u + k;
      int t = e < lim ? e : 0;
      int se = __shfl(idx, t, 64);
      float c0 = __shfl(sc, t, 64);
      w[k] = e < lim ? c0 : 0.f;
      const u16* r = G12 + (size_t)se * 384;
      va[k] = *(const ushort4*)(r + c1);
      vb[k] = *(const ushort2*)(r + 256 + c2);
    }
#pragma unroll
    for (int k = 0; k < 4; ++k){
      acc[0] += bf2f(va[k].x) * w[k];
      acc[1] += bf2f(va[k].y) * w[k];
      acc[2] += bf2f(va[k].z) * w[k];
      acc[3] += bf2f(va[k].w) * w[k];
      acc[4] += bf2f(vb[k].x) * w[k];
      acc[5] += bf2f(vb[k].y) * w[k];
    }
  }
  for (int j = b0 + 64; j < b1; ++j){
    int se = csr[j];
    float c0 = s_oi[se];
    const u16* r = G12 + (size_t)se * 384;
    ushort4 va = *(const ushort4*)(r + c1);
    ushort2 vb = *(const ushort2*)(r + 256 + c2);
    acc[0] += bf2f(va.x) * c0; acc[1] += bf2f(va.y) * c0;
    acc[2] += bf2f(va.z) * c0; acc[3] += bf2f(va.w) * c0;
    acc[4] += bf2f(vb.x) * c0; acc[5] += bf2f(vb.y) * c0;
  }
  float sii = s_ii[wave], sob = s_ob[wave];
  float4 bb1 = *(const float4*)(b1i + c1);
  f32x2 bb2 = *(const f32x2*)(b2i + c2);
  u16x4 o1;
  o1.x = f2bf(fmaxf(acc[0] * sii + bb1.x, 0.f) * sob);
  o1.y = f2bf(fmaxf(acc[1] * sii + bb1.y, 0.f) * sob);
  o1.z = f2bf(fmaxf(acc[2] * sii + bb1.z, 0.f) * sob);
  o1.w = f2bf(fmaxf(acc[3] * sii + bb1.w, 0.f) * sob);
  __builtin_nontemporal_store(o1, (u16x4*)(Ha + (size_t)wave * 256 + c1));
  f32x2 o2 = {acc[4] * sii + bb2.x, acc[5] * sii + bb2.y};
  __builtin_nontemporal_store(o2, (f32x2*)(outa + (size_t)wave * 128 + c2));
}

// ================= standalone GEMM (for out_b) =============================
__global__ __launch_bounds__(256) void gemm_kernel(
    const float* __restrict__ A,
    const u16* __restrict__ PWH, const u16* __restrict__ PWL,
    const float* __restrict__ bias, const float* __restrict__ rs,
    float* __restrict__ Cf, u16* __restrict__ C16,
    int M, int nT, int wpsShift, int doRelu, int ldC, int colOff){
  gemm_dev(blockIdx.x, A, PWH, PWL, bias, rs, Cf, C16,
           M, nT, wpsShift, doRelu, ldC, colOff);
}

extern "C" void kernel_launch(void* const* d_in, const int* in_sizes, int n_in,
                              void* d_out, int out_size, void* d_ws, size_t ws_size,
                              hipStream_t stream){
  const float* x_a = (const float*)d_in[0];
  const float* x_b = (const float*)d_in[1];
  const float* W1b = (const float*)d_in[2];
  const float* b1b = (const float*)d_in[3];
  const float* W1i = (const float*)d_in[4];
  const float* b1i = (const float*)d_in[5];
  const float* W2b = (const float*)d_in[6];
  const float* b2b = (const float*)d_in[7];
  const float* W2i = (const float*)d_in[8];
  const float* b2i = (const float*)d_in[9];
  const int* bs  = (const int*)d_in[10];
  const int* bd  = (const int*)d_in[11];
  const int* isc = (const int*)d_in[12];
  const int* idt = (const int*)d_in[13];

  char* w = (char*)d_ws;
  size_t o = 0;
  auto take = [&](size_t bytes) -> void* {
    void* p = w + o; o = (o + bytes + 255) & ~(size_t)255; return p;
  };
  int* zint = (int*)take(120000 * sizeof(int));   // 4 degree counters
  int* c_bs = zint, *c_bd = zint + 50000, *c_is = zint + 60000, *c_id = zint + 70000;
  int* rank_bel = (int*)take(NE * sizeof(int));
  int* rank_inc = (int*)take(NE * sizeof(int));
  int* off_bel = (int*)take((NB + 1) * sizeof(int));
  int* off_inc = (int*)take((NA + 1) * sizeof(int));
  int* csr_bel = (int*)take(NE * sizeof(int));
  int* csr_inc = (int*)take(NE * sizeof(int));
  float* s_ob = (float*)take(NA * sizeof(float));
  float* s_ib = (float*)take(NB * sizeof(float));
  float* s_oi = (float*)take(NB * sizeof(float));
  float* s_ii = (float*)take(NA * sizeof(float));
  u16* pwh = (u16*)take(196608 * sizeof(u16));
  u16* pwl = (u16*)take(196608 * sizeof(u16));
  u16* pwh1b = pwh, *pwh1i = pwh + 65536, *pwh2b = pwh + 131072, *pwh2i = pwh + 163840;
  u16* pwl1b = pwl, *pwl1i = pwl + 65536, *pwl2b = pwl + 131072, *pwl2i = pwl + 163840;
  u16* xa16 = (u16*)take((size_t)NA * 256 * sizeof(u16));   // x_a bf16 (unscaled)
  u16* G12  = (u16*)take((size_t)NB * 384 * sizeof(u16));   // [G1 256 | G2 128] bf16
  u16* H_a  = (u16*)take((size_t)NA * 256 * sizeof(u16));   // relu(L1 inc)*s_ob, bf16
  float* P_b = (float*)take((size_t)NB * 256 * sizeof(float)); // bel agg out (reused)

  float* out_a = (float*)d_out;                     // [NA,128]
  float* out_b = (float*)d_out + (size_t)NA * 128;  // [NB,128]

  // ---- setup ----
  pre_kernel<<<256, 256, 0, stream>>>(zint, 120000, W1i, pwh, pwl);
  // [G1 gemm | hist+ranks | pack W1b/W2b/W2i | cvt x_a] in ONE dispatch
  mega_kernel<<<GB + HB + PB + CB, 256, 0, stream>>>(
      x_b, pwh1i, pwl1i, G12,
      bs, bd, isc, idt, c_bs, c_bd, c_is, c_id, rank_bel, rank_inc,
      W1b, W2b, W2i, pwh, pwl, x_a, xa16);
  scan_scales_kernel<<<52, 1024, 0, stream>>>(c_bs, c_bd, c_is, c_id,
                                              off_bel, off_inc,
                                              s_ob, s_ib, s_oi, s_ii);
  fill_kernel<<<1172, 256, 0, stream>>>(bs, bd, isc, idt, rank_bel, rank_inc,
                                        off_bel, off_inc, csr_bel, csr_inc);
  // ---- compute ----
  // P_b = agg_bel(xa16 * s_ob[src])
  agg_bel_kernel<<<2500, 256, 0, stream>>>(xa16, s_ob, off_bel, csr_bel, P_b, NB);
  // H_b (LDS-only) = relu((P_b@W1b)*s_ib+b1b); G2 = H_b@W2i -> G12 cols 256..
  gemmHG_kernel<<<625, 256, 0, stream>>>(P_b, pwh1b, pwl1b, b1b, s_ib,
                                         pwh2i, pwl2i, G12);
  // merged inc agg (weight s_oi[src]): H_a (bf16, pre-scaled s_ob) + out_a
  agg_inc2_kernel<<<12500, 256, 0, stream>>>(G12, off_inc, csr_inc, s_oi,
                                             s_ii, s_ob, b1i, b2i, H_a, out_a);
  // P_b = agg_bel(H_a)  (H_a already src-scaled)
  agg_bel_kernel<<<2500, 256, 0, stream>>>(H_a, nullptr, off_bel, csr_bel, P_b, NB);
  // out_b = (P_b@W2b)*s_ib + b2b
  gemm_kernel<<<625, 256, 0, stream>>>(P_b, pwh2b, pwl2b, b2b, s_ib,
                                       out_b, nullptr, NB, 8, 2, 0, 128, 0);
}